// Round 10
// baseline (402.411 us; speedup 1.0000x reference)
//
#include <hip/hip_runtime.h>

#define DD 128
#define NHEAD 8
#define DH 16
#define EPS 1e-5f
#define BSH 9                 // bucket width 512 nodes
#define BWIDTH 512
#define NBLK1 256             // pass-1 blocks

// ---------- bf16 helpers (OCP bf16 = f32 upper half, RNE) ----------
__device__ inline float4 up4(ushort4 u) {
    return make_float4(__uint_as_float((unsigned)u.x << 16),
                       __uint_as_float((unsigned)u.y << 16),
                       __uint_as_float((unsigned)u.z << 16),
                       __uint_as_float((unsigned)u.w << 16));
}
__device__ inline unsigned short f2b(float f) {
    unsigned u = __float_as_uint(f);
    u += 0x7fffu + ((u >> 16) & 1);
    return (unsigned short)(u >> 16);
}

// LDS swizzle for transposed tiles (row space 64): word(k,r) = k*64 + (r ^ (((k>>2)&7)<<2)).
__device__ inline int qw(int k, int r) { return (k << 6) + (r ^ (((k >> 2) & 7) << 2)); }

// ================= h -> bf16 copy =================
__global__ void k_h2b(const float4* __restrict__ h4, ushort4* __restrict__ hb, int n4) {
    int i = blockIdx.x * 256 + threadIdx.x;
    if (i < n4) {
        float4 v = h4[i];
        hb[i] = make_ushort4(f2b(v.x), f2b(v.y), f2b(v.z), f2b(v.w));
    }
}

// ================= pass 1a: per-block bucket histograms =================
__global__ __launch_bounds__(256) void k_p1count(
        const int* __restrict__ gs, const int* __restrict__ gd,
        const int* __restrict__ as_, const int* __restrict__ ad,
        int* __restrict__ blkcnt, int E, int N, int Btot) {
    __shared__ int cnts[512];
    for (int j = threadIdx.x; j < 2 * Btot; j += 256) cnts[j] = 0;
    __syncthreads();
    int E2 = 2 * E;
    for (int i = blockIdx.x * 256 + threadIdx.x; i < E2; i += NBLK1 * 256) {
        int g = (i >= E);
        int e = g ? i - E : i;
        int s = g ? as_[e] : gs[e];
        int d = g ? ad[e] : gd[e];
        int cd = d + g * N, cs = s + g * N;
        atomicAdd(&cnts[cd >> BSH], 1);
        atomicAdd(&cnts[Btot + (cs >> BSH)], 1);
    }
    __syncthreads();
    for (int j = threadIdx.x; j < 2 * Btot; j += 256)
        blkcnt[j * NBLK1 + blockIdx.x] = cnts[j];
}

// ================= 3-stage scan =================
__global__ void k_scan1(const int* __restrict__ cnt, int* __restrict__ outv,
                        int* __restrict__ part, int n) {
    __shared__ int wsums[4];
    int t = threadIdx.x;
    int base = blockIdx.x * 1024 + t * 4;
    int v0 = 0, v1 = 0, v2 = 0, v3 = 0;
    if (base + 3 < n) {
        int4 q = *(const int4*)(cnt + base);
        v0 = q.x; v1 = q.y; v2 = q.z; v3 = q.w;
    } else {
        if (base < n)     v0 = cnt[base];
        if (base + 1 < n) v1 = cnt[base + 1];
        if (base + 2 < n) v2 = cnt[base + 2];
        if (base + 3 < n) v3 = cnt[base + 3];
    }
    int s0 = v0, s1 = s0 + v1, s2 = s1 + v2, s3 = s2 + v3;
    int x = s3;
    int lane = t & 63, w = t >> 6;
    for (int o = 1; o < 64; o <<= 1) { int u = __shfl_up(x, o); if (lane >= o) x += u; }
    if (lane == 63) wsums[w] = x;
    __syncthreads();
    int wo = 0;
    for (int i = 0; i < w; ++i) wo += wsums[i];
    int excl = wo + x - s3;
    if (base < n)     outv[base]     = excl;
    if (base + 1 < n) outv[base + 1] = excl + s0;
    if (base + 2 < n) outv[base + 2] = excl + s1;
    if (base + 3 < n) outv[base + 3] = excl + s2;
    if (t == 255) part[blockIdx.x] = wo + x;
}

__global__ void k_scan2(int* __restrict__ part, int nb) {
    __shared__ int ws[4];
    int t = threadIdx.x;
    int v = (t < nb) ? part[t] : 0;
    int x = v;
    int lane = t & 63, w = t >> 6;
    for (int o = 1; o < 64; o <<= 1) { int u = __shfl_up(x, o); if (lane >= o) x += u; }
    if (lane == 63) ws[w] = x;
    __syncthreads();
    int wo = 0;
    for (int i = 0; i < w; ++i) wo += ws[i];
    if (t < nb) part[t] = wo + x - v;
}

__global__ void k_scan3(int* __restrict__ outv, const int* __restrict__ part, int n, int total) {
    int i = blockIdx.x * blockDim.x + threadIdx.x;
    if (i < n) outv[i] += part[i >> 10];
    if (i == 0) outv[n] = total;
}

// ================= pass 1b: scatter edges into bucket regions =================
__global__ __launch_bounds__(256) void k_p1scatter(
        const int* __restrict__ gs, const int* __restrict__ gd,
        const int* __restrict__ as_, const int* __restrict__ ad,
        const int* __restrict__ scn, int2* __restrict__ pairs, int* __restrict__ svals,
        int E, int N, int Btot) {
    __shared__ int cur[512];
    for (int j = threadIdx.x; j < 2 * Btot; j += 256)
        cur[j] = scn[j * NBLK1 + blockIdx.x];
    __syncthreads();
    int E2 = 2 * E;
    for (int i = blockIdx.x * 256 + threadIdx.x; i < E2; i += NBLK1 * 256) {
        int g = (i >= E);
        int e = g ? i - E : i;
        int s = g ? as_[e] : gs[e];
        int d = g ? ad[e] : gd[e];
        int cd = d + g * N, cs = s + g * N;
        int pd = atomicAdd(&cur[cd >> BSH], 1);
        pairs[pd] = make_int2(cd, s);
        int ps = atomicAdd(&cur[Btot + (cs >> BSH)], 1);
        svals[ps - E2] = cs;
    }
}

// ================= pass 2: per-bucket CSR + indeg + norms =================
__global__ __launch_bounds__(256) void k_p2(
        const int2* __restrict__ pairs, const int* __restrict__ svals,
        const int* __restrict__ scn, int* __restrict__ rowptr, int* __restrict__ csr,
        float* __restrict__ indeg, float* __restrict__ norms,
        int E, int N2, int Btot) {
    __shared__ int hist[BWIDTH];
    __shared__ int offs[BWIDTH];
    __shared__ int cur[BWIDTH];
    __shared__ int ws4[4];
    int b = blockIdx.x, t = threadIdx.x;
    int node0 = b << BSH;
    int W = N2 - node0; if (W > BWIDTH) W = BWIDTH;
    int Sd = scn[b * NBLK1], Ed = scn[(b + 1) * NBLK1];
    hist[t] = 0; hist[t + 256] = 0;
    __syncthreads();
    for (int i = Sd + t; i < Ed; i += 256) {
        int2 p = pairs[i];
        atomicAdd(&hist[p.x - node0], 1);
    }
    __syncthreads();
    int a0 = hist[2 * t], a1 = hist[2 * t + 1];
    int sum2 = a0 + a1;
    int lane = t & 63, w = t >> 6;
    int x = sum2;
    for (int o = 1; o < 64; o <<= 1) { int u = __shfl_up(x, o); if (lane >= o) x += u; }
    if (lane == 63) ws4[w] = x;
    __syncthreads();
    int wo = 0;
    for (int i = 0; i < w; ++i) wo += ws4[i];
    int excl2 = wo + x - sum2;
    offs[2 * t] = excl2; offs[2 * t + 1] = excl2 + a0;
    cur[t] = 0; cur[t + 256] = 0;
    __syncthreads();
    for (int j = t; j < W; j += 256) {
        rowptr[node0 + j] = Sd + offs[j];
        indeg[node0 + j] = (float)hist[j];
    }
    if (b == 0 && t == 0) rowptr[N2] = 2 * E;
    for (int i = Sd + t; i < Ed; i += 256) {
        int2 p = pairs[i];
        int l = p.x - node0;
        int pos = atomicAdd(&cur[l], 1);
        csr[Sd + offs[l] + pos] = p.y;
    }
    __syncthreads();
    hist[t] = 0; hist[t + 256] = 0;
    __syncthreads();
    int Ss = scn[(Btot + b) * NBLK1] - 2 * E;
    int Es = scn[(Btot + b + 1) * NBLK1] - 2 * E;
    for (int i = Ss + t; i < Es; i += 256)
        atomicAdd(&hist[svals[i] - node0], 1);
    __syncthreads();
    for (int j = t; j < W; j += 256) {
        int od = hist[j];
        norms[node0 + j] = od > 0 ? rsqrtf((float)od) : 0.f;
    }
}

// ================= pull: avg (SAGE), index-prefetch pipelined =================
__global__ __launch_bounds__(256) void k_pull_avg(
        const ushort4* __restrict__ xb, const int* __restrict__ rowptr,
        const int* __restrict__ csr, const float* __restrict__ norm_s,
        ushort4* __restrict__ outb, int N, int doscale) {
    int node = blockIdx.x * 8 + (threadIdx.x >> 5);
    int lane = threadIdx.x & 31;
    if (node >= N) return;
    int beg = rowptr[node], end = rowptr[node + 1];
    float4 a = up4(xb[(size_t)node * 32 + lane]);          // self term
    int e = beg;
    int nb = end - e; if (nb > 32) nb = 32;
    int idx = (lane < nb) ? csr[e + lane] : 0;
    while (nb > 0) {
        int en = e + nb;
        int nbn = end - en; if (nbn > 32) nbn = 32;
        int idxn = (lane < nbn) ? csr[en + lane] : 0;      // prefetch next chunk
        #pragma unroll 8
        for (int d = 0; d < nb; ++d) {
            int s = __shfl(idx, d, 32);
            float4 v = up4(xb[(size_t)s * 32 + lane]);
            a.x += v.x; a.y += v.y; a.z += v.z; a.w += v.w;
        }
        e = en; nb = nbn; idx = idxn;
    }
    float sc = 1.f / (float)(end - beg + 1);
    if (doscale) sc *= norm_s[node];
    outb[(size_t)node * 32 + lane] =
        make_ushort4(f2b(a.x * sc), f2b(a.y * sc), f2b(a.z * sc), f2b(a.w * sc));
}

// ================= pull: sum of pre-scaled bf16 rows -> f32 Q, + ssum =================
__global__ __launch_bounds__(256) void k_pull3(
        const ushort4* __restrict__ Pb, const int* __restrict__ rowptr,
        const int* __restrict__ csr, const float* __restrict__ norm_s,
        float4* __restrict__ Q, float* __restrict__ ssum, int N) {
    int node = blockIdx.x * 8 + (threadIdx.x >> 5);
    int lane = threadIdx.x & 31;
    if (node >= N) return;
    int beg = rowptr[node], end = rowptr[node + 1];
    float4 a = make_float4(0.f, 0.f, 0.f, 0.f);
    float ss = 0.f;
    int e = beg;
    int nb = end - e; if (nb > 32) nb = 32;
    int idx = (lane < nb) ? csr[e + lane] : 0;
    while (nb > 0) {
        int en = e + nb;
        int nbn = end - en; if (nbn > 32) nbn = 32;
        int idxn = (lane < nbn) ? csr[en + lane] : 0;
        #pragma unroll 8
        for (int d = 0; d < nb; ++d) {
            int s = __shfl(idx, d, 32);
            float4 v = up4(Pb[(size_t)s * 32 + lane]);
            a.x += v.x; a.y += v.y; a.z += v.z; a.w += v.w;
            ss += norm_s[s];
        }
        e = en; nb = nbn; idx = idxn;
    }
    Q[(size_t)node * 32 + lane] = a;
    if (lane == 0) ssum[node] = ss;
}

// ================= weight pre-combination =================
__global__ void k_wcomb(const float* __restrict__ A, const float* __restrict__ B,
                        float* __restrict__ C) {          // C[i] = A[i](128x128) @ B[i](128x16)
    int i = blockIdx.x;
    const float* Ai = A + (size_t)i * DD * DD;
    const float* Bi = B + (size_t)i * DD * DH;
    float* Ci = C + (size_t)i * DD * DH;
    for (int o = threadIdx.x; o < DD * DH; o += blockDim.x) {
        int r = o >> 4, c = o & 15;
        float acc = 0.f;
        #pragma unroll 8
        for (int k = 0; k < DD; ++k) acc += Ai[r * DD + k] * Bi[k * DH + c];
        Ci[o] = acc;
    }
}

// transposed variant: Mt[k][head*16+c] = (A[i] @ B[i])[k][c]
__global__ void k_wcombT(const float* __restrict__ A, const float* __restrict__ B,
                         float* __restrict__ Mt) {
    int i = blockIdx.x;
    const float* Ai = A + (size_t)i * DD * DD;
    const float* Bi = B + (size_t)i * DD * DH;
    for (int o = threadIdx.x; o < DD * DH; o += blockDim.x) {
        int r = o >> 4, c = o & 15;
        float acc = 0.f;
        #pragma unroll 8
        for (int k = 0; k < DD; ++k) acc += Ai[r * DD + k] * Bi[k * DH + c];
        Mt[r * DD + i * DH + c] = acc;
    }
}

__global__ void k_cvec(const float* __restrict__ b1, const float* __restrict__ b2,
                       const float* __restrict__ T, const float* __restrict__ W3,
                       float* __restrict__ cvec) {
    int idx = blockIdx.x * blockDim.x + threadIdx.x;
    if (idx >= NHEAD * DH) return;
    int i = idx >> 4, c = idx & 15;
    float acc = 0.f;
    for (int k = 0; k < DD; ++k)
        acc += b1[i * DD + k] * T[(size_t)i * DD * DH + k * DH + c]
             + b2[i * DD + k] * W3[(size_t)i * DD * DH + k * DH + c];
    cvec[idx] = acc;
}

// ================= fused tail: 512 thr, 64 rows/block, 4x4 register tiles ==========
// Thread (tr=t>>5 in [0,16), tc=t&31): rows 4tr..+3, cols 4tc..+3.
// LDS: qT[2][128*64] (64KB) + ws[32][128] (16KB) = 80KB -> 2 blocks/CU, 16 waves/CU.
__global__ __launch_bounds__(512) void k_tail(
        const float4* __restrict__ Qgt4, const float4* __restrict__ Qat4,
        const float* __restrict__ ssum, const float* __restrict__ indeg,
        const float* __restrict__ Mt, const float* __restrict__ cvec,
        const float* __restrict__ b3, const float* __restrict__ h,
        const float* __restrict__ ln_g, const float* __restrict__ ln_b,
        const float* __restrict__ fW1, const float* __restrict__ Fb1,
        const float* __restrict__ fW2, const float* __restrict__ Fb2,
        float* __restrict__ out, int N) {
    __shared__ float qT[2][DD * 64];      // [graph][swizzled k*64+r], 65536 B
    __shared__ float ws[32][DD];          // 16384 B
    int t = threadIdx.x;
    int tc = t & 31, tr = t >> 5;         // tr in [0,16)
    int C0 = 4 * tc, R0 = 4 * tr;
    int row0 = blockIdx.x * 64;

    // ---- stage Q transposed (swizzled scalar writes) ----
    #pragma unroll
    for (int i = 0; i < 4; ++i) {
        int idx = t + 512 * i;
        int r = idx & 63, c = idx >> 6;
        int gr = row0 + r; if (gr >= N) gr = N - 1;
        float4 q0 = Qgt4[(size_t)gr * 32 + c];
        float4 q1 = Qat4[(size_t)gr * 32 + c];
        int rx = r ^ ((c & 7) << 2);
        qT[0][(4 * c + 0) * 64 + rx] = q0.x; qT[0][(4 * c + 1) * 64 + rx] = q0.y;
        qT[0][(4 * c + 2) * 64 + rx] = q0.z; qT[0][(4 * c + 3) * 64 + rx] = q0.w;
        qT[1][(4 * c + 0) * 64 + rx] = q1.x; qT[1][(4 * c + 1) * 64 + rx] = q1.y;
        qT[1][(4 * c + 2) * 64 + rx] = q1.z; qT[1][(4 * c + 3) * 64 + rx] = q1.w;
    }
    int g = (C0 >> 5) & 1;      // graph of this thread's 4 columns

    // ---- GEMM1: xcat = Q_g @ M ----
    float acc[4][4] = {};
    for (int kt = 0; kt < 4; ++kt) {
        __syncthreads();
        const float4* wsrc = (const float4*)(Mt + kt * 32 * DD);
        float4* wdst = (float4*)&ws[0][0];
        #pragma unroll
        for (int i = 0; i < 2; ++i) wdst[t + 512 * i] = wsrc[t + 512 * i];
        __syncthreads();
        #pragma unroll 4
        for (int kk = 0; kk < 32; ++kk) {
            float4 av = *(const float4*)&qT[g][qw(kt * 32 + kk, R0)];
            float4 bv = *(const float4*)&ws[kk][C0];
            acc[0][0] += av.x * bv.x; acc[0][1] += av.x * bv.y;
            acc[0][2] += av.x * bv.z; acc[0][3] += av.x * bv.w;
            acc[1][0] += av.y * bv.x; acc[1][1] += av.y * bv.y;
            acc[1][2] += av.y * bv.z; acc[1][3] += av.y * bv.w;
            acc[2][0] += av.z * bv.x; acc[2][1] += av.z * bv.y;
            acc[2][2] += av.z * bv.z; acc[2][3] += av.z * bv.w;
            acc[3][0] += av.w * bv.x; acc[3][1] += av.w * bv.y;
            acc[3][2] += av.w * bv.z; acc[3][3] += av.w * bv.w;
        }
    }
    // ---- epilogue1: (acc + ss*c)*nd + b3, LN over row, + residual ----
    float4 cv  = *(const float4*)&cvec[C0];
    float4 b3v = *(const float4*)&b3[C0];
    float4 glv = *(const float4*)&ln_g[C0];
    float4 blv = *(const float4*)&ln_b[C0];
    float xr[4][4];
    #pragma unroll
    for (int i = 0; i < 4; ++i) {
        int row = row0 + R0 + i;
        int rc = row < N ? row : N - 1;
        float ss = ssum[g * N + rc];
        float id = indeg[g * N + rc];
        float nd = id > 0.f ? rsqrtf(id) : 0.f;
        float v0 = (acc[i][0] + ss * cv.x) * nd + b3v.x;
        float v1 = (acc[i][1] + ss * cv.y) * nd + b3v.y;
        float v2 = (acc[i][2] + ss * cv.z) * nd + b3v.z;
        float v3 = (acc[i][3] + ss * cv.w) * nd + b3v.w;
        float s = v0 + v1 + v2 + v3;
        float s2 = v0 * v0 + v1 * v1 + v2 * v2 + v3 * v3;
        for (int o = 16; o > 0; o >>= 1) { s += __shfl_xor(s, o); s2 += __shfl_xor(s2, o); }
        float mu = s * (1.f / DD);
        float var = s2 * (1.f / DD) - mu * mu;
        float rs = rsqrtf(var + EPS);
        float4 hv = *(const float4*)&h[(size_t)rc * DD + C0];
        xr[i][0] = hv.x + (v0 - mu) * rs * glv.x + blv.x;
        xr[i][1] = hv.y + (v1 - mu) * rs * glv.y + blv.y;
        xr[i][2] = hv.z + (v2 - mu) * rs * glv.z + blv.z;
        xr[i][3] = hv.w + (v3 - mu) * rs * glv.w + blv.w;
    }
    __syncthreads();                       // all qT reads done before overwrite
    {
        int rx = R0 ^ ((tc & 7) << 2);     // (k>>2)&7 = tc&7 for k = C0+j
        #pragma unroll
        for (int j = 0; j < 4; ++j)        // xT -> qT[0]
            *(float4*)&qT[0][(C0 + j) * 64 + rx] =
                make_float4(xr[0][j], xr[1][j], xr[2][j], xr[3][j]);
    }

    // ---- GEMM2: f1 = relu(x @ fW1 + Fb1) ----
    float ac2[4][4] = {};
    for (int kt = 0; kt < 4; ++kt) {
        __syncthreads();
        const float4* wsrc = (const float4*)(fW1 + kt * 32 * DD);
        float4* wdst = (float4*)&ws[0][0];
        #pragma unroll
        for (int i = 0; i < 2; ++i) wdst[t + 512 * i] = wsrc[t + 512 * i];
        __syncthreads();
        #pragma unroll 4
        for (int kk = 0; kk < 32; ++kk) {
            float4 av = *(const float4*)&qT[0][qw(kt * 32 + kk, R0)];
            float4 bv = *(const float4*)&ws[kk][C0];
            ac2[0][0] += av.x * bv.x; ac2[0][1] += av.x * bv.y;
            ac2[0][2] += av.x * bv.z; ac2[0][3] += av.x * bv.w;
            ac2[1][0] += av.y * bv.x; ac2[1][1] += av.y * bv.y;
            ac2[1][2] += av.y * bv.z; ac2[1][3] += av.y * bv.w;
            ac2[2][0] += av.z * bv.x; ac2[2][1] += av.z * bv.y;
            ac2[2][2] += av.z * bv.z; ac2[2][3] += av.z * bv.w;
            ac2[3][0] += av.w * bv.x; ac2[3][1] += av.w * bv.y;
            ac2[3][2] += av.w * bv.z; ac2[3][3] += av.w * bv.w;
        }
    }
    float4 fbv = *(const float4*)&Fb1[C0];
    __syncthreads();                       // order f1T writes after GEMM1 qT[1] reads
    {
        int rx = R0 ^ ((tc & 7) << 2);
        #pragma unroll
        for (int j = 0; j < 4; ++j) {      // f1T -> qT[1]
            float bj = j == 0 ? fbv.x : j == 1 ? fbv.y : j == 2 ? fbv.z : fbv.w;
            float w0 = ac2[0][j] + bj, w1 = ac2[1][j] + bj;
            float w2 = ac2[2][j] + bj, w3 = ac2[3][j] + bj;
            *(float4*)&qT[1][(C0 + j) * 64 + rx] =
                make_float4(w0 > 0.f ? w0 : 0.f, w1 > 0.f ? w1 : 0.f,
                            w2 > 0.f ? w2 : 0.f, w3 > 0.f ? w3 : 0.f);
        }
    }

    // ---- GEMM3: out = x + LN(f1 @ fW2 + Fb2) ----
    float ac3[4][4] = {};
    for (int kt = 0; kt < 4; ++kt) {
        __syncthreads();                   // orders f1T writes before reads (kt=0)
        const float4* wsrc = (const float4*)(fW2 + kt * 32 * DD);
        float4* wdst = (float4*)&ws[0][0];
        #pragma unroll
        for (int i = 0; i < 2; ++i) wdst[t + 512 * i] = wsrc[t + 512 * i];
        __syncthreads();
        #pragma unroll 4
        for (int kk = 0; kk < 32; ++kk) {
            float4 av = *(const float4*)&qT[1][qw(kt * 32 + kk, R0)];
            float4 bv = *(const float4*)&ws[kk][C0];
            ac3[0][0] += av.x * bv.x; ac3[0][1] += av.x * bv.y;
            ac3[0][2] += av.x * bv.z; ac3[0][3] += av.x * bv.w;
            ac3[1][0] += av.y * bv.x; ac3[1][1] += av.y * bv.y;
            ac3[1][2] += av.y * bv.z; ac3[1][3] += av.y * bv.w;
            ac3[2][0] += av.z * bv.x; ac3[2][1] += av.z * bv.y;
            ac3[2][2] += av.z * bv.z; ac3[2][3] += av.z * bv.w;
            ac3[3][0] += av.w * bv.x; ac3[3][1] += av.w * bv.y;
            ac3[3][2] += av.w * bv.z; ac3[3][3] += av.w * bv.w;
        }
    }
    float4 gbv = *(const float4*)&Fb2[C0];
    #pragma unroll
    for (int i = 0; i < 4; ++i) {
        int row = row0 + R0 + i;
        float v0 = ac3[i][0] + gbv.x;
        float v1 = ac3[i][1] + gbv.y;
        float v2 = ac3[i][2] + gbv.z;
        float v3 = ac3[i][3] + gbv.w;
        float s = v0 + v1 + v2 + v3;
        float s2 = v0 * v0 + v1 * v1 + v2 * v2 + v3 * v3;
        for (int o = 16; o > 0; o >>= 1) { s += __shfl_xor(s, o); s2 += __shfl_xor(s2, o); }
        float mu = s * (1.f / DD);
        float var = s2 * (1.f / DD) - mu * mu;
        float rs = rsqrtf(var + EPS);
        if (row < N) {
            *(float4*)&out[(size_t)row * DD + C0] =
                make_float4(xr[i][0] + (v0 - mu) * rs * glv.x + blv.x,
                            xr[i][1] + (v1 - mu) * rs * glv.y + blv.y,
                            xr[i][2] + (v2 - mu) * rs * glv.z + blv.z,
                            xr[i][3] + (v3 - mu) * rs * glv.w + blv.w);
        }
    }
}

extern "C" void kernel_launch(void* const* d_in, const int* in_sizes, int n_in,
                              void* d_out, int out_size, void* d_ws, size_t ws_size,
                              hipStream_t stream) {
    const float* h      = (const float*)d_in[0];
    const int*   gt_src = (const int*)d_in[1];
    const int*   gt_dst = (const int*)d_in[2];
    const int*   at_src = (const int*)d_in[3];
    const int*   at_dst = (const int*)d_in[4];
    const float* W1     = (const float*)d_in[5];
    const float* b1     = (const float*)d_in[6];
    const float* W2     = (const float*)d_in[7];
    const float* b2     = (const float*)d_in[8];
    const float* W3     = (const float*)d_in[9];
    const float* b3     = (const float*)d_in[10];
    const float* fW1    = (const float*)d_in[11];
    const float* fb1    = (const float*)d_in[12];
    const float* fW2    = (const float*)d_in[13];
    const float* fb2    = (const float*)d_in[14];
    const float* ln_g   = (const float*)d_in[15];
    const float* ln_b   = (const float*)d_in[16];

    const int E = in_sizes[1];
    const int N = in_sizes[0] / DD;
    const size_t NB = (size_t)N * DD;
    const int N2 = 2 * N;
    const int Btot = (N2 + BWIDTH - 1) >> BSH;
    const int n1 = 2 * Btot * NBLK1;

    // ---- workspace layout ----
    float* w = (float*)d_ws;
    float* Qgt = w;                              // NB f32 (25.6 MB)
    unsigned short* hb    = (unsigned short*)(Qgt + NB);   // NB bf16
    unsigned short* bufAb = hb + NB;                       // NB bf16
    unsigned short* bufBb = bufAb + NB;                    // NB bf16
    float* sm = (float*)(bufBb + NB);
    float* norms = sm;  sm += N2;
    float* indeg = sm;  sm += N2;
    float* ssum  = sm;  sm += N2;
    float* Tm    = sm;  sm += (size_t)NHEAD * DD * DH;
    float* Mt    = sm;  sm += DD * DD;
    float* cvec  = sm;  sm += NHEAD * DH + 32;
    int* ip = (int*)sm;
    int* rowptr = ip;  ip += ((N2 + 1 + 3) & ~3);
    int* csr    = ip;  ip += 2 * E;
    int* blkcnt = ip;  ip += ((n1 + 1 + 3) & ~3);
    int* scn    = ip;  ip += ((n1 + 1 + 3) & ~3);
    int* part   = ip;  ip += 256;
    // CSR-build scratch aliased over Qgt (written only later, in pass 3)
    int2* pairs = (int2*)Qgt;                    // 2E int2 = 9.6 MB
    int*  svals = (int*)(pairs + 2 * E);         // 2E int  = 4.8 MB
    float* Qat  = (float*)d_out;                 // reuse d_out; overwritten by k_tail

    // weight pre-combination
    k_wcomb <<<NHEAD, 256, 0, stream>>>(W2, W3, Tm);
    k_wcombT<<<NHEAD, 256, 0, stream>>>(W1, Tm, Mt);
    k_cvec  <<<1, 128, 0, stream>>>(b1, b2, Tm, W3, cvec);

    const int TB = 256;
    // h -> bf16
    k_h2b<<<(int)(NB / 4 + TB - 1) / TB, TB, 0, stream>>>((const float4*)h, (ushort4*)hb,
                                                          (int)(NB / 4));
    // CSR build (no global atomics)
    k_p1count<<<NBLK1, 256, 0, stream>>>(gt_src, gt_dst, at_src, at_dst, blkcnt, E, N, Btot);
    int nsb = (n1 + 1023) / 1024;
    k_scan1<<<nsb, 256, 0, stream>>>(blkcnt, scn, part, n1);
    k_scan2<<<1, 256, 0, stream>>>(part, nsb);
    k_scan3<<<(n1 + TB - 1) / TB, TB, 0, stream>>>(scn, part, n1, 4 * E);
    k_p1scatter<<<NBLK1, 256, 0, stream>>>(gt_src, gt_dst, at_src, at_dst, scn,
                                           pairs, svals, E, N, Btot);
    k_p2<<<Btot, 256, 0, stream>>>(pairs, svals, scn, rowptr, csr, indeg, norms,
                                   E, N2, Btot);

    // pull passes (bf16 gathers, pipelined): 8 nodes/block, 32 lanes/node
    const int pgrid = (N + 7) / 8;
    for (int g = 0; g < 2; ++g) {
        const int* rp = rowptr + g * N;
        const float* ns = norms + g * N;
        float* Q = g ? Qat : Qgt;
        k_pull_avg<<<pgrid, 256, 0, stream>>>((const ushort4*)hb, rp, csr, ns,
                                              (ushort4*)bufAb, N, 0);
        k_pull_avg<<<pgrid, 256, 0, stream>>>((const ushort4*)bufAb, rp, csr, ns,
                                              (ushort4*)bufBb, N, 1);
        k_pull3<<<pgrid, 256, 0, stream>>>((const ushort4*)bufBb, rp, csr, ns,
                                           (float4*)Q, ssum + g * N, N);
    }

    // fused dense tail (64 rows/block, 512 threads, 4x4 register tiles, swizzled LDS)
    k_tail<<<(N + 63) / 64, 512, 0, stream>>>((const float4*)Qgt, (const float4*)Qat,
                                              ssum, indeg, Mt, cvec, b3, h, ln_g, ln_b,
                                              fW1, fb1, fW2, fb2, (float*)d_out, N);
}

// Round 11
// 337.896 us; speedup vs baseline: 1.1909x; 1.1909x over previous
//
#include <hip/hip_runtime.h>

#define DD 128
#define NHEAD 8
#define DH 16
#define EPS 1e-5f
#define BSH 9                 // bucket width 512 nodes
#define BWIDTH 512
#define NBLK1 256             // pass-1 blocks

typedef __attribute__((ext_vector_type(8))) short bf16x8;   // 8 bf16 = 4 VGPR
typedef __attribute__((ext_vector_type(4))) float f32x4;

// ---------- bf16 helpers (OCP bf16 = f32 upper half, RNE) ----------
__device__ inline float4 up4(ushort4 u) {
    return make_float4(__uint_as_float((unsigned)u.x << 16),
                       __uint_as_float((unsigned)u.y << 16),
                       __uint_as_float((unsigned)u.z << 16),
                       __uint_as_float((unsigned)u.w << 16));
}
__device__ inline unsigned short f2b(float f) {
    unsigned u = __float_as_uint(f);
    u += 0x7fffu + ((u >> 16) & 1);
    return (unsigned short)(u >> 16);
}

// XOR swizzle for bf16 MFMA panels (row stride 256 B): keeps 16B alignment.
#define SWZB(row, off) ((off) ^ (((row) & 7) << 4))

// ================= h -> bf16 copy =================
__global__ void k_h2b(const float4* __restrict__ h4, ushort4* __restrict__ hb, int n4) {
    int i = blockIdx.x * 256 + threadIdx.x;
    if (i < n4) {
        float4 v = h4[i];
        hb[i] = make_ushort4(f2b(v.x), f2b(v.y), f2b(v.z), f2b(v.w));
    }
}

// ================= pass 1a: per-block bucket histograms =================
__global__ __launch_bounds__(256) void k_p1count(
        const int* __restrict__ gs, const int* __restrict__ gd,
        const int* __restrict__ as_, const int* __restrict__ ad,
        int* __restrict__ blkcnt, int E, int N, int Btot) {
    __shared__ int cnts[512];
    for (int j = threadIdx.x; j < 2 * Btot; j += 256) cnts[j] = 0;
    __syncthreads();
    int E2 = 2 * E;
    for (int i = blockIdx.x * 256 + threadIdx.x; i < E2; i += NBLK1 * 256) {
        int g = (i >= E);
        int e = g ? i - E : i;
        int s = g ? as_[e] : gs[e];
        int d = g ? ad[e] : gd[e];
        int cd = d + g * N, cs = s + g * N;
        atomicAdd(&cnts[cd >> BSH], 1);
        atomicAdd(&cnts[Btot + (cs >> BSH)], 1);
    }
    __syncthreads();
    for (int j = threadIdx.x; j < 2 * Btot; j += 256)
        blkcnt[j * NBLK1 + blockIdx.x] = cnts[j];
}

// ================= 3-stage scan =================
__global__ void k_scan1(const int* __restrict__ cnt, int* __restrict__ outv,
                        int* __restrict__ part, int n) {
    __shared__ int wsums[4];
    int t = threadIdx.x;
    int base = blockIdx.x * 1024 + t * 4;
    int v0 = 0, v1 = 0, v2 = 0, v3 = 0;
    if (base + 3 < n) {
        int4 q = *(const int4*)(cnt + base);
        v0 = q.x; v1 = q.y; v2 = q.z; v3 = q.w;
    } else {
        if (base < n)     v0 = cnt[base];
        if (base + 1 < n) v1 = cnt[base + 1];
        if (base + 2 < n) v2 = cnt[base + 2];
        if (base + 3 < n) v3 = cnt[base + 3];
    }
    int s0 = v0, s1 = s0 + v1, s2 = s1 + v2, s3 = s2 + v3;
    int x = s3;
    int lane = t & 63, w = t >> 6;
    for (int o = 1; o < 64; o <<= 1) { int u = __shfl_up(x, o); if (lane >= o) x += u; }
    if (lane == 63) wsums[w] = x;
    __syncthreads();
    int wo = 0;
    for (int i = 0; i < w; ++i) wo += wsums[i];
    int excl = wo + x - s3;
    if (base < n)     outv[base]     = excl;
    if (base + 1 < n) outv[base + 1] = excl + s0;
    if (base + 2 < n) outv[base + 2] = excl + s1;
    if (base + 3 < n) outv[base + 3] = excl + s2;
    if (t == 255) part[blockIdx.x] = wo + x;
}

__global__ void k_scan2(int* __restrict__ part, int nb) {
    __shared__ int ws[4];
    int t = threadIdx.x;
    int v = (t < nb) ? part[t] : 0;
    int x = v;
    int lane = t & 63, w = t >> 6;
    for (int o = 1; o < 64; o <<= 1) { int u = __shfl_up(x, o); if (lane >= o) x += u; }
    if (lane == 63) ws[w] = x;
    __syncthreads();
    int wo = 0;
    for (int i = 0; i < w; ++i) wo += ws[i];
    if (t < nb) part[t] = wo + x - v;
}

__global__ void k_scan3(int* __restrict__ outv, const int* __restrict__ part, int n, int total) {
    int i = blockIdx.x * blockDim.x + threadIdx.x;
    if (i < n) outv[i] += part[i >> 10];
    if (i == 0) outv[n] = total;
}

// ================= pass 1b: scatter edges into bucket regions =================
__global__ __launch_bounds__(256) void k_p1scatter(
        const int* __restrict__ gs, const int* __restrict__ gd,
        const int* __restrict__ as_, const int* __restrict__ ad,
        const int* __restrict__ scn, int2* __restrict__ pairs, int* __restrict__ svals,
        int E, int N, int Btot) {
    __shared__ int cur[512];
    for (int j = threadIdx.x; j < 2 * Btot; j += 256)
        cur[j] = scn[j * NBLK1 + blockIdx.x];
    __syncthreads();
    int E2 = 2 * E;
    for (int i = blockIdx.x * 256 + threadIdx.x; i < E2; i += NBLK1 * 256) {
        int g = (i >= E);
        int e = g ? i - E : i;
        int s = g ? as_[e] : gs[e];
        int d = g ? ad[e] : gd[e];
        int cd = d + g * N, cs = s + g * N;
        int pd = atomicAdd(&cur[cd >> BSH], 1);
        pairs[pd] = make_int2(cd, s);
        int ps = atomicAdd(&cur[Btot + (cs >> BSH)], 1);
        svals[ps - E2] = cs;
    }
}

// ================= pass 2: per-bucket CSR + indeg + norms =================
__global__ __launch_bounds__(256) void k_p2(
        const int2* __restrict__ pairs, const int* __restrict__ svals,
        const int* __restrict__ scn, int* __restrict__ rowptr, int* __restrict__ csr,
        float* __restrict__ indeg, float* __restrict__ norms,
        int E, int N2, int Btot) {
    __shared__ int hist[BWIDTH];
    __shared__ int offs[BWIDTH];
    __shared__ int cur[BWIDTH];
    __shared__ int ws4[4];
    int b = blockIdx.x, t = threadIdx.x;
    int node0 = b << BSH;
    int W = N2 - node0; if (W > BWIDTH) W = BWIDTH;
    int Sd = scn[b * NBLK1], Ed = scn[(b + 1) * NBLK1];
    hist[t] = 0; hist[t + 256] = 0;
    __syncthreads();
    for (int i = Sd + t; i < Ed; i += 256) {
        int2 p = pairs[i];
        atomicAdd(&hist[p.x - node0], 1);
    }
    __syncthreads();
    int a0 = hist[2 * t], a1 = hist[2 * t + 1];
    int sum2 = a0 + a1;
    int lane = t & 63, w = t >> 6;
    int x = sum2;
    for (int o = 1; o < 64; o <<= 1) { int u = __shfl_up(x, o); if (lane >= o) x += u; }
    if (lane == 63) ws4[w] = x;
    __syncthreads();
    int wo = 0;
    for (int i = 0; i < w; ++i) wo += ws4[i];
    int excl2 = wo + x - sum2;
    offs[2 * t] = excl2; offs[2 * t + 1] = excl2 + a0;
    cur[t] = 0; cur[t + 256] = 0;
    __syncthreads();
    for (int j = t; j < W; j += 256) {
        rowptr[node0 + j] = Sd + offs[j];
        indeg[node0 + j] = (float)hist[j];
    }
    if (b == 0 && t == 0) rowptr[N2] = 2 * E;
    for (int i = Sd + t; i < Ed; i += 256) {
        int2 p = pairs[i];
        int l = p.x - node0;
        int pos = atomicAdd(&cur[l], 1);
        csr[Sd + offs[l] + pos] = p.y;
    }
    __syncthreads();
    hist[t] = 0; hist[t + 256] = 0;
    __syncthreads();
    int Ss = scn[(Btot + b) * NBLK1] - 2 * E;
    int Es = scn[(Btot + b + 1) * NBLK1] - 2 * E;
    for (int i = Ss + t; i < Es; i += 256)
        atomicAdd(&hist[svals[i] - node0], 1);
    __syncthreads();
    for (int j = t; j < W; j += 256) {
        int od = hist[j];
        norms[node0 + j] = od > 0 ? rsqrtf((float)od) : 0.f;
    }
}

// ================= pull: avg (SAGE), index-prefetch pipelined =================
__global__ __launch_bounds__(256) void k_pull_avg(
        const ushort4* __restrict__ xb, const int* __restrict__ rowptr,
        const int* __restrict__ csr, const float* __restrict__ norm_s,
        ushort4* __restrict__ outb, int N, int doscale) {
    int node = blockIdx.x * 8 + (threadIdx.x >> 5);
    int lane = threadIdx.x & 31;
    if (node >= N) return;
    int beg = rowptr[node], end = rowptr[node + 1];
    float4 a = up4(xb[(size_t)node * 32 + lane]);          // self term
    int e = beg;
    int nb = end - e; if (nb > 32) nb = 32;
    int idx = (lane < nb) ? csr[e + lane] : 0;
    while (nb > 0) {
        int en = e + nb;
        int nbn = end - en; if (nbn > 32) nbn = 32;
        int idxn = (lane < nbn) ? csr[en + lane] : 0;      // prefetch next chunk
        #pragma unroll 8
        for (int d = 0; d < nb; ++d) {
            int s = __shfl(idx, d, 32);
            float4 v = up4(xb[(size_t)s * 32 + lane]);
            a.x += v.x; a.y += v.y; a.z += v.z; a.w += v.w;
        }
        e = en; nb = nbn; idx = idxn;
    }
    float sc = 1.f / (float)(end - beg + 1);
    if (doscale) sc *= norm_s[node];
    outb[(size_t)node * 32 + lane] =
        make_ushort4(f2b(a.x * sc), f2b(a.y * sc), f2b(a.z * sc), f2b(a.w * sc));
}

// ================= pull: sum of pre-scaled bf16 rows -> bf16 Q, + ssum =================
__global__ __launch_bounds__(256) void k_pull3(
        const ushort4* __restrict__ Pb, const int* __restrict__ rowptr,
        const int* __restrict__ csr, const float* __restrict__ norm_s,
        ushort4* __restrict__ Qb, float* __restrict__ ssum, int N) {
    int node = blockIdx.x * 8 + (threadIdx.x >> 5);
    int lane = threadIdx.x & 31;
    if (node >= N) return;
    int beg = rowptr[node], end = rowptr[node + 1];
    float4 a = make_float4(0.f, 0.f, 0.f, 0.f);
    float ss = 0.f;
    int e = beg;
    int nb = end - e; if (nb > 32) nb = 32;
    int idx = (lane < nb) ? csr[e + lane] : 0;
    while (nb > 0) {
        int en = e + nb;
        int nbn = end - en; if (nbn > 32) nbn = 32;
        int idxn = (lane < nbn) ? csr[en + lane] : 0;
        #pragma unroll 8
        for (int d = 0; d < nb; ++d) {
            int s = __shfl(idx, d, 32);
            float4 v = up4(Pb[(size_t)s * 32 + lane]);
            a.x += v.x; a.y += v.y; a.z += v.z; a.w += v.w;
            ss += norm_s[s];
        }
        e = en; nb = nbn; idx = idxn;
    }
    Qb[(size_t)node * 32 + lane] = make_ushort4(f2b(a.x), f2b(a.y), f2b(a.z), f2b(a.w));
    if (lane == 0) ssum[node] = ss;
}

// ================= weight pre-combination =================
__global__ void k_wcomb(const float* __restrict__ A, const float* __restrict__ B,
                        float* __restrict__ C) {          // C[i] = A[i](128x128) @ B[i](128x16)
    int i = blockIdx.x;
    const float* Ai = A + (size_t)i * DD * DD;
    const float* Bi = B + (size_t)i * DD * DH;
    float* Ci = C + (size_t)i * DD * DH;
    for (int o = threadIdx.x; o < DD * DH; o += blockDim.x) {
        int r = o >> 4, c = o & 15;
        float acc = 0.f;
        #pragma unroll 8
        for (int k = 0; k < DD; ++k) acc += Ai[r * DD + k] * Bi[k * DH + c];
        Ci[o] = acc;
    }
}

// combined M = W1@T, written TRANSPOSED in bf16: Mtb[(head*16+c)*128 + k]
__global__ void k_wcombTB(const float* __restrict__ A, const float* __restrict__ B,
                          unsigned short* __restrict__ Mtb) {
    int i = blockIdx.x;
    const float* Ai = A + (size_t)i * DD * DD;
    const float* Bi = B + (size_t)i * DD * DH;
    for (int o = threadIdx.x; o < DD * DH; o += blockDim.x) {
        int r = o >> 4, c = o & 15;        // r = k index, c = col within head
        float acc = 0.f;
        #pragma unroll 8
        for (int k = 0; k < DD; ++k) acc += Ai[r * DD + k] * Bi[k * DH + c];
        Mtb[(size_t)(i * DH + c) * DD + r] = f2b(acc);
    }
}

// transpose + bf16 a 128x128 f32 weight: Wtb[c*128+k] = bf16(W[k*128+c])
__global__ void k_wtb(const float* __restrict__ W, unsigned short* __restrict__ Wtb) {
    int idx = blockIdx.x * 256 + threadIdx.x;
    if (idx < DD * DD) {
        int c = idx >> 7, k = idx & 127;
        Wtb[c * DD + k] = f2b(W[(size_t)k * DD + c]);
    }
}

__global__ void k_cvec(const float* __restrict__ b1, const float* __restrict__ b2,
                       const float* __restrict__ T, const float* __restrict__ W3,
                       float* __restrict__ cvec) {
    int idx = blockIdx.x * blockDim.x + threadIdx.x;
    if (idx >= NHEAD * DH) return;
    int i = idx >> 4, c = idx & 15;
    float acc = 0.f;
    for (int k = 0; k < DD; ++k)
        acc += b1[i * DD + k] * T[(size_t)i * DD * DH + k * DH + c]
             + b2[i * DD + k] * W3[(size_t)i * DD * DH + k * DH + c];
    cvec[idx] = acc;
}

// ================= fused tail, MFMA bf16: 64 rows/block, 4 waves =================
// Wave w owns rows w*16..+15, all 8 col-tiles. Per K-step: 2 A-frags + 8 B-frags + 8 MFMA.
// A-frag: lane row=l&15, k=(l>>4)*8+[0..8) from row-major bf16 panel (256B rows, SWZB).
// B-frag: lane col=l&15, same k, from pre-transposed weights [col][k].
// C/D: col=lane&15, row=(lane>>4)*4+reg  [m89 verified].
__global__ __launch_bounds__(256) void k_tailm(
        const unsigned short* __restrict__ Qgtb, const unsigned short* __restrict__ Qatb,
        const float* __restrict__ ssum, const float* __restrict__ indeg,
        const unsigned short* __restrict__ Mtb, const unsigned short* __restrict__ W1tb,
        const unsigned short* __restrict__ W2tb,
        const float* __restrict__ cvec, const float* __restrict__ b3,
        const float* __restrict__ h, const float* __restrict__ ln_g,
        const float* __restrict__ ln_b, const float* __restrict__ Fb1,
        const float* __restrict__ Fb2, float* __restrict__ out, int N) {
    __shared__ __align__(16) unsigned short A0[64 * DD];   // 16 KB: Qgt -> x panel
    __shared__ __align__(16) unsigned short A1[64 * DD];   // 16 KB: Qat -> f1 panel
    __shared__ __align__(16) unsigned short Bt[DD * DD];   // 32 KB: weight panel [col][k]
    int t = threadIdx.x;
    int w = t >> 6, l = t & 63;
    int lm = l & 15, lk = l >> 4;
    int row0 = blockIdx.x * 64;

    // ---- stage A panels (Q bf16, swizzled) ----
    for (int i = t; i < 1024; i += 256) {
        int r = i >> 4, ch = i & 15;
        int gr = row0 + r; if (gr >= N) gr = N - 1;
        uint4 v0 = *(const uint4*)(Qgtb + (size_t)gr * DD + ch * 8);
        uint4 v1 = *(const uint4*)(Qatb + (size_t)gr * DD + ch * 8);
        *(uint4*)((char*)A0 + r * 256 + SWZB(r, ch * 16)) = v0;
        *(uint4*)((char*)A1 + r * 256 + SWZB(r, ch * 16)) = v1;
    }
    // ---- stage Bt = Mtb ----
    for (int i = t; i < 2048; i += 256) {
        int c = i >> 4, ch = i & 15;
        uint4 v = *(const uint4*)(Mtb + (size_t)c * DD + ch * 8);
        *(uint4*)((char*)Bt + c * 256 + SWZB(c, ch * 16)) = v;
    }
    __syncthreads();

    int arow = w * 16 + lm;
    int abase = arow * 256;

    // ---- GEMM1 ----
    f32x4 acc[8];
    #pragma unroll
    for (int i = 0; i < 8; ++i) acc[i] = (f32x4){0.f, 0.f, 0.f, 0.f};
    #pragma unroll
    for (int kt = 0; kt < 4; ++kt) {
        int aoff = abase + SWZB(arow, kt * 64 + lk * 16);
        bf16x8 ag = *(const bf16x8*)((const char*)A0 + aoff);
        bf16x8 aa = *(const bf16x8*)((const char*)A1 + aoff);
        #pragma unroll
        for (int ct = 0; ct < 8; ++ct) {
            int bc = ct * 16 + lm;
            bf16x8 b = *(const bf16x8*)((const char*)Bt + bc * 256 + SWZB(bc, kt * 64 + lk * 16));
            acc[ct] = __builtin_amdgcn_mfma_f32_16x16x32_bf16(
                ((ct >> 1) & 1) ? aa : ag, b, acc[ct], 0, 0, 0);
        }
    }

    // ---- epilogue 1: (acc + ss*c)*nd + b3, LN over 128 cols, + h residual ----
    int rbase = row0 + w * 16 + lk * 4;
    float ssv[2][4], ndv[2][4];
    #pragma unroll
    for (int i = 0; i < 4; ++i) {
        int rc = rbase + i; if (rc >= N) rc = N - 1;
        #pragma unroll
        for (int g2 = 0; g2 < 2; ++g2) {
            ssv[g2][i] = ssum[g2 * N + rc];
            float id = indeg[g2 * N + rc];
            ndv[g2][i] = id > 0.f ? rsqrtf(id) : 0.f;
        }
    }
    float glr[8], blr[8];
    #pragma unroll
    for (int ct = 0; ct < 8; ++ct) {
        glr[ct] = ln_g[ct * 16 + lm];
        blr[ct] = ln_b[ct * 16 + lm];
    }
    float vv[8][4];
    float s[4] = {0, 0, 0, 0}, s2[4] = {0, 0, 0, 0};
    #pragma unroll
    for (int ct = 0; ct < 8; ++ct) {
        int col = ct * 16 + lm;
        int g2 = (ct >> 1) & 1;
        float cvv = cvec[col], b3v = b3[col];
        #pragma unroll
        for (int i = 0; i < 4; ++i) {
            float v = (acc[ct][i] + ssv[g2][i] * cvv) * ndv[g2][i] + b3v;
            vv[ct][i] = v;
            s[i] += v; s2[i] += v * v;
        }
    }
    #pragma unroll
    for (int o = 8; o > 0; o >>= 1) {
        #pragma unroll
        for (int i = 0; i < 4; ++i) {
            s[i] += __shfl_xor(s[i], o);
            s2[i] += __shfl_xor(s2[i], o);
        }
    }
    __syncthreads();                        // all GEMM1 LDS reads done
    float xk[8][4];
    #pragma unroll
    for (int i = 0; i < 4; ++i) {
        float mu = s[i] * (1.f / DD);
        float var = s2[i] * (1.f / DD) - mu * mu;
        float rs = rsqrtf(var + EPS);
        int row = rbase + i; int rc = row < N ? row : N - 1;
        int lrow = w * 16 + lk * 4 + i;
        #pragma unroll
        for (int ct = 0; ct < 8; ++ct) {
            int col = ct * 16 + lm;
            float x = h[(size_t)rc * DD + col] + (vv[ct][i] - mu) * rs * glr[ct] + blr[ct];
            xk[ct][i] = x;
            *(unsigned short*)((char*)A0 + lrow * 256 + SWZB(lrow, 2 * col)) = f2b(x);
        }
    }
    for (int i = t; i < 2048; i += 256) {   // stage Bt = W1tb
        int c = i >> 4, ch = i & 15;
        uint4 v = *(const uint4*)(W1tb + (size_t)c * DD + ch * 8);
        *(uint4*)((char*)Bt + c * 256 + SWZB(c, ch * 16)) = v;
    }
    __syncthreads();

    // ---- GEMM2: f1 = relu(x @ fW1 + Fb1) ----
    f32x4 ac2[8];
    #pragma unroll
    for (int i = 0; i < 8; ++i) ac2[i] = (f32x4){0.f, 0.f, 0.f, 0.f};
    #pragma unroll
    for (int kt = 0; kt < 4; ++kt) {
        bf16x8 a = *(const bf16x8*)((const char*)A0 + abase + SWZB(arow, kt * 64 + lk * 16));
        #pragma unroll
        for (int ct = 0; ct < 8; ++ct) {
            int bc = ct * 16 + lm;
            bf16x8 b = *(const bf16x8*)((const char*)Bt + bc * 256 + SWZB(bc, kt * 64 + lk * 16));
            ac2[ct] = __builtin_amdgcn_mfma_f32_16x16x32_bf16(a, b, ac2[ct], 0, 0, 0);
        }
    }
    #pragma unroll
    for (int i = 0; i < 4; ++i) {
        int lrow = w * 16 + lk * 4 + i;
        #pragma unroll
        for (int ct = 0; ct < 8; ++ct) {
            int col = ct * 16 + lm;
            float f = ac2[ct][i] + Fb1[col];
            *(unsigned short*)((char*)A1 + lrow * 256 + SWZB(lrow, 2 * col)) =
                f2b(f > 0.f ? f : 0.f);
        }
    }
    __syncthreads();                        // GEMM2 Bt reads + f1 writes done
    for (int i = t; i < 2048; i += 256) {   // stage Bt = W2tb
        int c = i >> 4, ch = i & 15;
        uint4 v = *(const uint4*)(W2tb + (size_t)c * DD + ch * 8);
        *(uint4*)((char*)Bt + c * 256 + SWZB(c, ch * 16)) = v;
    }
    __syncthreads();

    // ---- GEMM3: out = x + LN(f1 @ fW2 + Fb2) ----
    f32x4 ac3[8];
    #pragma unroll
    for (int i = 0; i < 8; ++i) ac3[i] = (f32x4){0.f, 0.f, 0.f, 0.f};
    #pragma unroll
    for (int kt = 0; kt < 4; ++kt) {
        bf16x8 a = *(const bf16x8*)((const char*)A1 + abase + SWZB(arow, kt * 64 + lk * 16));
        #pragma unroll
        for (int ct = 0; ct < 8; ++ct) {
            int bc = ct * 16 + lm;
            bf16x8 b = *(const bf16x8*)((const char*)Bt + bc * 256 + SWZB(bc, kt * 64 + lk * 16));
            ac3[ct] = __builtin_amdgcn_mfma_f32_16x16x32_bf16(a, b, ac3[ct], 0, 0, 0);
        }
    }
    float v3[8][4];
    float s3[4] = {0, 0, 0, 0}, s32[4] = {0, 0, 0, 0};
    #pragma unroll
    for (int ct = 0; ct < 8; ++ct) {
        float fb = Fb2[ct * 16 + lm];
        #pragma unroll
        for (int i = 0; i < 4; ++i) {
            float v = ac3[ct][i] + fb;
            v3[ct][i] = v;
            s3[i] += v; s32[i] += v * v;
        }
    }
    #pragma unroll
    for (int o = 8; o > 0; o >>= 1) {
        #pragma unroll
        for (int i = 0; i < 4; ++i) {
            s3[i] += __shfl_xor(s3[i], o);
            s32[i] += __shfl_xor(s32[i], o);
        }
    }
    #pragma unroll
    for (int i = 0; i < 4; ++i) {
        float mu = s3[i] * (1.f / DD);
        float var = s32[i] * (1.f / DD) - mu * mu;
        float rs = rsqrtf(var + EPS);
        int row = rbase + i;
        if (row < N) {
            #pragma unroll
            for (int ct = 0; ct < 8; ++ct) {
                int col = ct * 16 + lm;
                out[(size_t)row * DD + col] = xk[ct][i] + (v3[ct][i] - mu) * rs * glr[ct] + blr[ct];
            }
        }
    }
}

extern "C" void kernel_launch(void* const* d_in, const int* in_sizes, int n_in,
                              void* d_out, int out_size, void* d_ws, size_t ws_size,
                              hipStream_t stream) {
    const float* h      = (const float*)d_in[0];
    const int*   gt_src = (const int*)d_in[1];
    const int*   gt_dst = (const int*)d_in[2];
    const int*   at_src = (const int*)d_in[3];
    const int*   at_dst = (const int*)d_in[4];
    const float* W1     = (const float*)d_in[5];
    const float* b1     = (const float*)d_in[6];
    const float* W2     = (const float*)d_in[7];
    const float* b2     = (const float*)d_in[8];
    const float* W3     = (const float*)d_in[9];
    const float* b3     = (const float*)d_in[10];
    const float* fW1    = (const float*)d_in[11];
    const float* fb1    = (const float*)d_in[12];
    const float* fW2    = (const float*)d_in[13];
    const float* fb2    = (const float*)d_in[14];
    const float* ln_g   = (const float*)d_in[15];
    const float* ln_b   = (const float*)d_in[16];

    const int E = in_sizes[1];
    const int N = in_sizes[0] / DD;
    const size_t NB = (size_t)N * DD;
    const int N2 = 2 * N;
    const int Btot = (N2 + BWIDTH - 1) >> BSH;
    const int n1 = 2 * Btot * NBLK1;

    // ---- workspace layout (bf16 node tables) ----
    unsigned short* Qgtb  = (unsigned short*)d_ws;         // NB bf16 (12.8 MB)
    unsigned short* Qatb  = Qgtb + NB;                     // NB bf16
    unsigned short* hb    = Qatb + NB;                     // NB bf16
    unsigned short* bufAb = hb + NB;                       // NB bf16
    unsigned short* bufBb = bufAb + NB;                    // NB bf16
    float* sm = (float*)(bufBb + NB);
    float* norms = sm;  sm += N2;
    float* indeg = sm;  sm += N2;
    float* ssum  = sm;  sm += N2;
    float* Tm    = sm;  sm += (size_t)NHEAD * DD * DH;
    float* cvec  = sm;  sm += NHEAD * DH + 32;
    unsigned short* Mtb  = (unsigned short*)sm;
    unsigned short* W1tb = Mtb + DD * DD;
    unsigned short* W2tb = W1tb + DD * DD;
    int* ip = (int*)(W2tb + DD * DD);
    int* rowptr = ip;  ip += ((N2 + 1 + 3) & ~3);
    int* csr    = ip;  ip += 2 * E;
    int* blkcnt = ip;  ip += ((n1 + 1 + 3) & ~3);
    int* scn    = ip;  ip += ((n1 + 1 + 3) & ~3);
    int* part   = ip;  ip += 256;
    // CSR-build scratch aliased over Qgtb/Qatb (14.4 MB < 25.6 MB; written before pulls)
    int2* pairs = (int2*)Qgtb;
    int*  svals = (int*)(pairs + 2 * E);

    // weight pre-combination / transposed bf16 weights
    k_wcomb  <<<NHEAD, 256, 0, stream>>>(W2, W3, Tm);
    k_wcombTB<<<NHEAD, 256, 0, stream>>>(W1, Tm, Mtb);
    k_cvec   <<<1, 128, 0, stream>>>(b1, b2, Tm, W3, cvec);
    k_wtb    <<<64, 256, 0, stream>>>(fW1, W1tb);
    k_wtb    <<<64, 256, 0, stream>>>(fW2, W2tb);

    const int TB = 256;
    // h -> bf16
    k_h2b<<<(int)(NB / 4 + TB - 1) / TB, TB, 0, stream>>>((const float4*)h, (ushort4*)hb,
                                                          (int)(NB / 4));
    // CSR build (no global atomics)
    k_p1count<<<NBLK1, 256, 0, stream>>>(gt_src, gt_dst, at_src, at_dst, blkcnt, E, N, Btot);
    int nsb = (n1 + 1023) / 1024;
    k_scan1<<<nsb, 256, 0, stream>>>(blkcnt, scn, part, n1);
    k_scan2<<<1, 256, 0, stream>>>(part, nsb);
    k_scan3<<<(n1 + TB - 1) / TB, TB, 0, stream>>>(scn, part, n1, 4 * E);
    k_p1scatter<<<NBLK1, 256, 0, stream>>>(gt_src, gt_dst, at_src, at_dst, scn,
                                           pairs, svals, E, N, Btot);
    k_p2<<<Btot, 256, 0, stream>>>(pairs, svals, scn, rowptr, csr, indeg, norms,
                                   E, N2, Btot);

    // pull passes (bf16 gathers, pipelined): 8 nodes/block, 32 lanes/node
    const int pgrid = (N + 7) / 8;
    for (int g = 0; g < 2; ++g) {
        const int* rp = rowptr + g * N;
        const float* ns = norms + g * N;
        unsigned short* Qb = g ? Qatb : Qgtb;
        k_pull_avg<<<pgrid, 256, 0, stream>>>((const ushort4*)hb, rp, csr, ns,
                                              (ushort4*)bufAb, N, 0);
        k_pull_avg<<<pgrid, 256, 0, stream>>>((const ushort4*)bufAb, rp, csr, ns,
                                              (ushort4*)bufBb, N, 1);
        k_pull3<<<pgrid, 256, 0, stream>>>((const ushort4*)bufBb, rp, csr, ns,
                                           (ushort4*)Qb, ssum + g * N, N);
    }

    // fused dense tail (MFMA bf16, 64 rows/block, 256 threads)
    k_tailm<<<(N + 63) / 64, 256, 0, stream>>>(Qgtb, Qatb, ssum, indeg, Mtb, W1tb, W2tb,
                                               cvec, b3, h, ln_g, ln_b, fb1, fb2,
                                               (float*)d_out, N);
}

// Round 12
// 316.793 us; speedup vs baseline: 1.2703x; 1.0666x over previous
//
#include <hip/hip_runtime.h>

#define DD 128
#define NHEAD 8
#define DH 16
#define EPS 1e-5f
#define BSH 9                 // bucket width 512 nodes
#define BWIDTH 512
#define NBLK1 256             // pass-1 blocks

typedef __attribute__((ext_vector_type(8))) short bf16x8;   // 8 bf16 = 4 VGPR
typedef __attribute__((ext_vector_type(4))) float f32x4;

// ---------- bf16 helpers (OCP bf16 = f32 upper half, RNE) ----------
__device__ inline float4 up4(ushort4 u) {
    return make_float4(__uint_as_float((unsigned)u.x << 16),
                       __uint_as_float((unsigned)u.y << 16),
                       __uint_as_float((unsigned)u.z << 16),
                       __uint_as_float((unsigned)u.w << 16));
}
__device__ inline unsigned short f2b(float f) {
    unsigned u = __float_as_uint(f);
    u += 0x7fffu + ((u >> 16) & 1);
    return (unsigned short)(u >> 16);
}

// XOR swizzle for bf16 MFMA panels (row stride 256 B): keeps 16B alignment.
#define SWZB(row, off) ((off) ^ (((row) & 7) << 4))

// ================= h -> bf16 copy =================
__global__ void k_h2b(const float4* __restrict__ h4, ushort4* __restrict__ hb, int n4) {
    int i = blockIdx.x * 256 + threadIdx.x;
    if (i < n4) {
        float4 v = h4[i];
        hb[i] = make_ushort4(f2b(v.x), f2b(v.y), f2b(v.z), f2b(v.w));
    }
}

// ================= pass 1a: per-block bucket histograms =================
__global__ __launch_bounds__(256) void k_p1count(
        const int* __restrict__ gs, const int* __restrict__ gd,
        const int* __restrict__ as_, const int* __restrict__ ad,
        int* __restrict__ blkcnt, int E, int N, int Btot) {
    __shared__ int cnts[512];
    for (int j = threadIdx.x; j < 2 * Btot; j += 256) cnts[j] = 0;
    __syncthreads();
    int E2 = 2 * E;
    for (int i = blockIdx.x * 256 + threadIdx.x; i < E2; i += NBLK1 * 256) {
        int g = (i >= E);
        int e = g ? i - E : i;
        int s = g ? as_[e] : gs[e];
        int d = g ? ad[e] : gd[e];
        int cd = d + g * N, cs = s + g * N;
        atomicAdd(&cnts[cd >> BSH], 1);
        atomicAdd(&cnts[Btot + (cs >> BSH)], 1);
    }
    __syncthreads();
    for (int j = threadIdx.x; j < 2 * Btot; j += 256)
        blkcnt[j * NBLK1 + blockIdx.x] = cnts[j];
}

// ================= 3-stage scan =================
__global__ void k_scan1(const int* __restrict__ cnt, int* __restrict__ outv,
                        int* __restrict__ part, int n) {
    __shared__ int wsums[4];
    int t = threadIdx.x;
    int base = blockIdx.x * 1024 + t * 4;
    int v0 = 0, v1 = 0, v2 = 0, v3 = 0;
    if (base + 3 < n) {
        int4 q = *(const int4*)(cnt + base);
        v0 = q.x; v1 = q.y; v2 = q.z; v3 = q.w;
    } else {
        if (base < n)     v0 = cnt[base];
        if (base + 1 < n) v1 = cnt[base + 1];
        if (base + 2 < n) v2 = cnt[base + 2];
        if (base + 3 < n) v3 = cnt[base + 3];
    }
    int s0 = v0, s1 = s0 + v1, s2 = s1 + v2, s3 = s2 + v3;
    int x = s3;
    int lane = t & 63, w = t >> 6;
    for (int o = 1; o < 64; o <<= 1) { int u = __shfl_up(x, o); if (lane >= o) x += u; }
    if (lane == 63) wsums[w] = x;
    __syncthreads();
    int wo = 0;
    for (int i = 0; i < w; ++i) wo += wsums[i];
    int excl = wo + x - s3;
    if (base < n)     outv[base]     = excl;
    if (base + 1 < n) outv[base + 1] = excl + s0;
    if (base + 2 < n) outv[base + 2] = excl + s1;
    if (base + 3 < n) outv[base + 3] = excl + s2;
    if (t == 255) part[blockIdx.x] = wo + x;
}

__global__ void k_scan2(int* __restrict__ part, int nb) {
    __shared__ int ws[4];
    int t = threadIdx.x;
    int v = (t < nb) ? part[t] : 0;
    int x = v;
    int lane = t & 63, w = t >> 6;
    for (int o = 1; o < 64; o <<= 1) { int u = __shfl_up(x, o); if (lane >= o) x += u; }
    if (lane == 63) ws[w] = x;
    __syncthreads();
    int wo = 0;
    for (int i = 0; i < w; ++i) wo += ws[i];
    if (t < nb) part[t] = wo + x - v;
}

__global__ void k_scan3(int* __restrict__ outv, const int* __restrict__ part, int n, int total) {
    int i = blockIdx.x * blockDim.x + threadIdx.x;
    if (i < n) outv[i] += part[i >> 10];
    if (i == 0) outv[n] = total;
}

// ================= pass 1b: scatter edges into bucket regions =================
__global__ __launch_bounds__(256) void k_p1scatter(
        const int* __restrict__ gs, const int* __restrict__ gd,
        const int* __restrict__ as_, const int* __restrict__ ad,
        const int* __restrict__ scn, int2* __restrict__ pairs, int* __restrict__ svals,
        int E, int N, int Btot) {
    __shared__ int cur[512];
    for (int j = threadIdx.x; j < 2 * Btot; j += 256)
        cur[j] = scn[j * NBLK1 + blockIdx.x];
    __syncthreads();
    int E2 = 2 * E;
    for (int i = blockIdx.x * 256 + threadIdx.x; i < E2; i += NBLK1 * 256) {
        int g = (i >= E);
        int e = g ? i - E : i;
        int s = g ? as_[e] : gs[e];
        int d = g ? ad[e] : gd[e];
        int cd = d + g * N, cs = s + g * N;
        int pd = atomicAdd(&cur[cd >> BSH], 1);
        pairs[pd] = make_int2(cd, s);
        int ps = atomicAdd(&cur[Btot + (cs >> BSH)], 1);
        svals[ps - E2] = cs;
    }
}

// ================= pass 2: per-bucket CSR + indeg + norms =================
__global__ __launch_bounds__(256) void k_p2(
        const int2* __restrict__ pairs, const int* __restrict__ svals,
        const int* __restrict__ scn, int* __restrict__ rowptr, int* __restrict__ csr,
        float* __restrict__ indeg, float* __restrict__ norms,
        int E, int N2, int Btot) {
    __shared__ int hist[BWIDTH];
    __shared__ int offs[BWIDTH];
    __shared__ int cur[BWIDTH];
    __shared__ int ws4[4];
    int b = blockIdx.x, t = threadIdx.x;
    int node0 = b << BSH;
    int W = N2 - node0; if (W > BWIDTH) W = BWIDTH;
    int Sd = scn[b * NBLK1], Ed = scn[(b + 1) * NBLK1];
    hist[t] = 0; hist[t + 256] = 0;
    __syncthreads();
    for (int i = Sd + t; i < Ed; i += 256) {
        int2 p = pairs[i];
        atomicAdd(&hist[p.x - node0], 1);
    }
    __syncthreads();
    int a0 = hist[2 * t], a1 = hist[2 * t + 1];
    int sum2 = a0 + a1;
    int lane = t & 63, w = t >> 6;
    int x = sum2;
    for (int o = 1; o < 64; o <<= 1) { int u = __shfl_up(x, o); if (lane >= o) x += u; }
    if (lane == 63) ws4[w] = x;
    __syncthreads();
    int wo = 0;
    for (int i = 0; i < w; ++i) wo += ws4[i];
    int excl2 = wo + x - sum2;
    offs[2 * t] = excl2; offs[2 * t + 1] = excl2 + a0;
    cur[t] = 0; cur[t + 256] = 0;
    __syncthreads();
    for (int j = t; j < W; j += 256) {
        rowptr[node0 + j] = Sd + offs[j];
        indeg[node0 + j] = (float)hist[j];
    }
    if (b == 0 && t == 0) rowptr[N2] = 2 * E;
    for (int i = Sd + t; i < Ed; i += 256) {
        int2 p = pairs[i];
        int l = p.x - node0;
        int pos = atomicAdd(&cur[l], 1);
        csr[Sd + offs[l] + pos] = p.y;
    }
    __syncthreads();
    hist[t] = 0; hist[t + 256] = 0;
    __syncthreads();
    int Ss = scn[(Btot + b) * NBLK1] - 2 * E;
    int Es = scn[(Btot + b + 1) * NBLK1] - 2 * E;
    for (int i = Ss + t; i < Es; i += 256)
        atomicAdd(&hist[svals[i] - node0], 1);
    __syncthreads();
    for (int j = t; j < W; j += 256) {
        int od = hist[j];
        norms[node0 + j] = od > 0 ? rsqrtf((float)od) : 0.f;
    }
}

// ======== fused pull stage (both graphs, combined dst space [0,2N)) ========
// shared_in=1: gather/self from shared table rows [0,N) (stage 1, input hb)
// shared_in=0: gather/self from combined table rows [0,2N) at offset g*N (stage 2)
__global__ __launch_bounds__(256) void k_pull_avgF(
        const ushort4* __restrict__ xb, const int* __restrict__ rowptr,
        const int* __restrict__ csr, const float* __restrict__ norms,
        ushort4* __restrict__ outb, int N, int shared_in, int doscale) {
    int cd = blockIdx.x * 8 + (threadIdx.x >> 5);
    int lane = threadIdx.x & 31;
    if (cd >= 2 * N) return;
    int gofs = (cd >= N) ? N : 0;
    int base = shared_in ? 0 : gofs;
    int beg = rowptr[cd], end = rowptr[cd + 1];
    float4 a = up4(xb[(size_t)(base + cd - gofs) * 32 + lane]);   // self term
    int e = beg;
    int nb = end - e; if (nb > 32) nb = 32;
    int idx = (lane < nb) ? csr[e + lane] : 0;
    while (nb > 0) {
        int en = e + nb;
        int nbn = end - en; if (nbn > 32) nbn = 32;
        int idxn = (lane < nbn) ? csr[en + lane] : 0;             // prefetch next chunk
        #pragma unroll 8
        for (int d = 0; d < nb; ++d) {
            int s = __shfl(idx, d, 32);
            float4 v = up4(xb[(size_t)(base + s) * 32 + lane]);
            a.x += v.x; a.y += v.y; a.z += v.z; a.w += v.w;
        }
        e = en; nb = nbn; idx = idxn;
    }
    float sc = 1.f / (float)(end - beg + 1);
    if (doscale) sc *= norms[cd];
    outb[(size_t)cd * 32 + lane] =
        make_ushort4(f2b(a.x * sc), f2b(a.y * sc), f2b(a.z * sc), f2b(a.w * sc));
}

// ======== fused pull stage 3: sum of pre-scaled rows -> bf16 Q (combined), + ssum ========
__global__ __launch_bounds__(256) void k_pull3F(
        const ushort4* __restrict__ Pb, const int* __restrict__ rowptr,
        const int* __restrict__ csr, const float* __restrict__ norms,
        ushort4* __restrict__ Qb, float* __restrict__ ssum, int N) {
    int cd = blockIdx.x * 8 + (threadIdx.x >> 5);
    int lane = threadIdx.x & 31;
    if (cd >= 2 * N) return;
    int base = (cd >= N) ? N : 0;
    int beg = rowptr[cd], end = rowptr[cd + 1];
    float4 a = make_float4(0.f, 0.f, 0.f, 0.f);
    float ss = 0.f;
    int e = beg;
    int nb = end - e; if (nb > 32) nb = 32;
    int idx = (lane < nb) ? csr[e + lane] : 0;
    while (nb > 0) {
        int en = e + nb;
        int nbn = end - en; if (nbn > 32) nbn = 32;
        int idxn = (lane < nbn) ? csr[en + lane] : 0;
        #pragma unroll 8
        for (int d = 0; d < nb; ++d) {
            int s = __shfl(idx, d, 32);
            float4 v = up4(Pb[(size_t)(base + s) * 32 + lane]);
            a.x += v.x; a.y += v.y; a.z += v.z; a.w += v.w;
            ss += norms[base + s];
        }
        e = en; nb = nbn; idx = idxn;
    }
    Qb[(size_t)cd * 32 + lane] = make_ushort4(f2b(a.x), f2b(a.y), f2b(a.z), f2b(a.w));
    if (lane == 0) ssum[cd] = ss;
}

// ================= weight pre-combination =================
__global__ void k_wcomb(const float* __restrict__ A, const float* __restrict__ B,
                        float* __restrict__ C) {          // C[i] = A[i](128x128) @ B[i](128x16)
    int i = blockIdx.x;
    const float* Ai = A + (size_t)i * DD * DD;
    const float* Bi = B + (size_t)i * DD * DH;
    float* Ci = C + (size_t)i * DD * DH;
    for (int o = threadIdx.x; o < DD * DH; o += blockDim.x) {
        int r = o >> 4, c = o & 15;
        float acc = 0.f;
        #pragma unroll 8
        for (int k = 0; k < DD; ++k) acc += Ai[r * DD + k] * Bi[k * DH + c];
        Ci[o] = acc;
    }
}

// combined M = W1@T, written TRANSPOSED in bf16: Mtb[(head*16+c)*128 + k]
__global__ void k_wcombTB(const float* __restrict__ A, const float* __restrict__ B,
                          unsigned short* __restrict__ Mtb) {
    int i = blockIdx.x;
    const float* Ai = A + (size_t)i * DD * DD;
    const float* Bi = B + (size_t)i * DD * DH;
    for (int o = threadIdx.x; o < DD * DH; o += blockDim.x) {
        int r = o >> 4, c = o & 15;        // r = k index, c = col within head
        float acc = 0.f;
        #pragma unroll 8
        for (int k = 0; k < DD; ++k) acc += Ai[r * DD + k] * Bi[k * DH + c];
        Mtb[(size_t)(i * DH + c) * DD + r] = f2b(acc);
    }
}

// transpose + bf16 a 128x128 f32 weight: Wtb[c*128+k] = bf16(W[k*128+c])
__global__ void k_wtb(const float* __restrict__ W, unsigned short* __restrict__ Wtb) {
    int idx = blockIdx.x * 256 + threadIdx.x;
    if (idx < DD * DD) {
        int c = idx >> 7, k = idx & 127;
        Wtb[c * DD + k] = f2b(W[(size_t)k * DD + c]);
    }
}

__global__ void k_cvec(const float* __restrict__ b1, const float* __restrict__ b2,
                       const float* __restrict__ T, const float* __restrict__ W3,
                       float* __restrict__ cvec) {
    int idx = blockIdx.x * blockDim.x + threadIdx.x;
    if (idx >= NHEAD * DH) return;
    int i = idx >> 4, c = idx & 15;
    float acc = 0.f;
    for (int k = 0; k < DD; ++k)
        acc += b1[i * DD + k] * T[(size_t)i * DD * DH + k * DH + c]
             + b2[i * DD + k] * W3[(size_t)i * DD * DH + k * DH + c];
    cvec[idx] = acc;
}

// ================= fused tail, MFMA bf16: 64 rows/block, 4 waves =================
__global__ __launch_bounds__(256) void k_tailm(
        const unsigned short* __restrict__ Qgtb, const unsigned short* __restrict__ Qatb,
        const float* __restrict__ ssum, const float* __restrict__ indeg,
        const unsigned short* __restrict__ Mtb, const unsigned short* __restrict__ W1tb,
        const unsigned short* __restrict__ W2tb,
        const float* __restrict__ cvec, const float* __restrict__ b3,
        const float* __restrict__ h, const float* __restrict__ ln_g,
        const float* __restrict__ ln_b, const float* __restrict__ Fb1,
        const float* __restrict__ Fb2, float* __restrict__ out, int N) {
    __shared__ __align__(16) unsigned short A0[64 * DD];   // 16 KB: Qgt -> x panel
    __shared__ __align__(16) unsigned short A1[64 * DD];   // 16 KB: Qat -> f1 panel
    __shared__ __align__(16) unsigned short Bt[DD * DD];   // 32 KB: weight panel [col][k]
    int t = threadIdx.x;
    int w = t >> 6, l = t & 63;
    int lm = l & 15, lk = l >> 4;
    int row0 = blockIdx.x * 64;

    // ---- stage A panels (Q bf16, swizzled) ----
    for (int i = t; i < 1024; i += 256) {
        int r = i >> 4, ch = i & 15;
        int gr = row0 + r; if (gr >= N) gr = N - 1;
        uint4 v0 = *(const uint4*)(Qgtb + (size_t)gr * DD + ch * 8);
        uint4 v1 = *(const uint4*)(Qatb + (size_t)gr * DD + ch * 8);
        *(uint4*)((char*)A0 + r * 256 + SWZB(r, ch * 16)) = v0;
        *(uint4*)((char*)A1 + r * 256 + SWZB(r, ch * 16)) = v1;
    }
    // ---- stage Bt = Mtb ----
    for (int i = t; i < 2048; i += 256) {
        int c = i >> 4, ch = i & 15;
        uint4 v = *(const uint4*)(Mtb + (size_t)c * DD + ch * 8);
        *(uint4*)((char*)Bt + c * 256 + SWZB(c, ch * 16)) = v;
    }
    __syncthreads();

    int arow = w * 16 + lm;
    int abase = arow * 256;

    // ---- GEMM1 ----
    f32x4 acc[8];
    #pragma unroll
    for (int i = 0; i < 8; ++i) acc[i] = (f32x4){0.f, 0.f, 0.f, 0.f};
    #pragma unroll
    for (int kt = 0; kt < 4; ++kt) {
        int aoff = abase + SWZB(arow, kt * 64 + lk * 16);
        bf16x8 ag = *(const bf16x8*)((const char*)A0 + aoff);
        bf16x8 aa = *(const bf16x8*)((const char*)A1 + aoff);
        #pragma unroll
        for (int ct = 0; ct < 8; ++ct) {
            int bc = ct * 16 + lm;
            bf16x8 b = *(const bf16x8*)((const char*)Bt + bc * 256 + SWZB(bc, kt * 64 + lk * 16));
            acc[ct] = __builtin_amdgcn_mfma_f32_16x16x32_bf16(
                ((ct >> 1) & 1) ? aa : ag, b, acc[ct], 0, 0, 0);
        }
    }

    // ---- epilogue 1: (acc + ss*c)*nd + b3, LN over 128 cols, + h residual ----
    int rbase = row0 + w * 16 + lk * 4;
    float ssv[2][4], ndv[2][4];
    #pragma unroll
    for (int i = 0; i < 4; ++i) {
        int rc = rbase + i; if (rc >= N) rc = N - 1;
        #pragma unroll
        for (int g2 = 0; g2 < 2; ++g2) {
            ssv[g2][i] = ssum[g2 * N + rc];
            float id = indeg[g2 * N + rc];
            ndv[g2][i] = id > 0.f ? rsqrtf(id) : 0.f;
        }
    }
    float glr[8], blr[8];
    #pragma unroll
    for (int ct = 0; ct < 8; ++ct) {
        glr[ct] = ln_g[ct * 16 + lm];
        blr[ct] = ln_b[ct * 16 + lm];
    }
    float vv[8][4];
    float s[4] = {0, 0, 0, 0}, s2[4] = {0, 0, 0, 0};
    #pragma unroll
    for (int ct = 0; ct < 8; ++ct) {
        int col = ct * 16 + lm;
        int g2 = (ct >> 1) & 1;
        float cvv = cvec[col], b3v = b3[col];
        #pragma unroll
        for (int i = 0; i < 4; ++i) {
            float v = (acc[ct][i] + ssv[g2][i] * cvv) * ndv[g2][i] + b3v;
            vv[ct][i] = v;
            s[i] += v; s2[i] += v * v;
        }
    }
    #pragma unroll
    for (int o = 8; o > 0; o >>= 1) {
        #pragma unroll
        for (int i = 0; i < 4; ++i) {
            s[i] += __shfl_xor(s[i], o);
            s2[i] += __shfl_xor(s2[i], o);
        }
    }
    __syncthreads();                        // all GEMM1 LDS reads done
    float xk[8][4];
    #pragma unroll
    for (int i = 0; i < 4; ++i) {
        float mu = s[i] * (1.f / DD);
        float var = s2[i] * (1.f / DD) - mu * mu;
        float rs = rsqrtf(var + EPS);
        int row = rbase + i; int rc = row < N ? row : N - 1;
        int lrow = w * 16 + lk * 4 + i;
        #pragma unroll
        for (int ct = 0; ct < 8; ++ct) {
            int col = ct * 16 + lm;
            float x = h[(size_t)rc * DD + col] + (vv[ct][i] - mu) * rs * glr[ct] + blr[ct];
            xk[ct][i] = x;
            *(unsigned short*)((char*)A0 + lrow * 256 + SWZB(lrow, 2 * col)) = f2b(x);
        }
    }
    for (int i = t; i < 2048; i += 256) {   // stage Bt = W1tb
        int c = i >> 4, ch = i & 15;
        uint4 v = *(const uint4*)(W1tb + (size_t)c * DD + ch * 8);
        *(uint4*)((char*)Bt + c * 256 + SWZB(c, ch * 16)) = v;
    }
    __syncthreads();

    // ---- GEMM2: f1 = relu(x @ fW1 + Fb1) ----
    f32x4 ac2[8];
    #pragma unroll
    for (int i = 0; i < 8; ++i) ac2[i] = (f32x4){0.f, 0.f, 0.f, 0.f};
    #pragma unroll
    for (int kt = 0; kt < 4; ++kt) {
        bf16x8 a = *(const bf16x8*)((const char*)A0 + abase + SWZB(arow, kt * 64 + lk * 16));
        #pragma unroll
        for (int ct = 0; ct < 8; ++ct) {
            int bc = ct * 16 + lm;
            bf16x8 b = *(const bf16x8*)((const char*)Bt + bc * 256 + SWZB(bc, kt * 64 + lk * 16));
            ac2[ct] = __builtin_amdgcn_mfma_f32_16x16x32_bf16(a, b, ac2[ct], 0, 0, 0);
        }
    }
    #pragma unroll
    for (int i = 0; i < 4; ++i) {
        int lrow = w * 16 + lk * 4 + i;
        #pragma unroll
        for (int ct = 0; ct < 8; ++ct) {
            int col = ct * 16 + lm;
            float f = ac2[ct][i] + Fb1[col];
            *(unsigned short*)((char*)A1 + lrow * 256 + SWZB(lrow, 2 * col)) =
                f2b(f > 0.f ? f : 0.f);
        }
    }
    __syncthreads();                        // GEMM2 Bt reads + f1 writes done
    for (int i = t; i < 2048; i += 256) {   // stage Bt = W2tb
        int c = i >> 4, ch = i & 15;
        uint4 v = *(const uint4*)(W2tb + (size_t)c * DD + ch * 8);
        *(uint4*)((char*)Bt + c * 256 + SWZB(c, ch * 16)) = v;
    }
    __syncthreads();

    // ---- GEMM3: out = x + LN(f1 @ fW2 + Fb2) ----
    f32x4 ac3[8];
    #pragma unroll
    for (int i = 0; i < 8; ++i) ac3[i] = (f32x4){0.f, 0.f, 0.f, 0.f};
    #pragma unroll
    for (int kt = 0; kt < 4; ++kt) {
        bf16x8 a = *(const bf16x8*)((const char*)A1 + abase + SWZB(arow, kt * 64 + lk * 16));
        #pragma unroll
        for (int ct = 0; ct < 8; ++ct) {
            int bc = ct * 16 + lm;
            bf16x8 b = *(const bf16x8*)((const char*)Bt + bc * 256 + SWZB(bc, kt * 64 + lk * 16));
            ac3[ct] = __builtin_amdgcn_mfma_f32_16x16x32_bf16(a, b, ac3[ct], 0, 0, 0);
        }
    }
    float v3[8][4];
    float s3[4] = {0, 0, 0, 0}, s32[4] = {0, 0, 0, 0};
    #pragma unroll
    for (int ct = 0; ct < 8; ++ct) {
        float fb = Fb2[ct * 16 + lm];
        #pragma unroll
        for (int i = 0; i < 4; ++i) {
            float v = ac3[ct][i] + fb;
            v3[ct][i] = v;
            s3[i] += v; s32[i] += v * v;
        }
    }
    #pragma unroll
    for (int o = 8; o > 0; o >>= 1) {
        #pragma unroll
        for (int i = 0; i < 4; ++i) {
            s3[i] += __shfl_xor(s3[i], o);
            s32[i] += __shfl_xor(s32[i], o);
        }
    }
    #pragma unroll
    for (int i = 0; i < 4; ++i) {
        float mu = s3[i] * (1.f / DD);
        float var = s32[i] * (1.f / DD) - mu * mu;
        float rs = rsqrtf(var + EPS);
        int row = rbase + i;
        if (row < N) {
            #pragma unroll
            for (int ct = 0; ct < 8; ++ct) {
                int col = ct * 16 + lm;
                out[(size_t)row * DD + col] = xk[ct][i] + (v3[ct][i] - mu) * rs * glr[ct] + blr[ct];
            }
        }
    }
}

extern "C" void kernel_launch(void* const* d_in, const int* in_sizes, int n_in,
                              void* d_out, int out_size, void* d_ws, size_t ws_size,
                              hipStream_t stream) {
    const float* h      = (const float*)d_in[0];
    const int*   gt_src = (const int*)d_in[1];
    const int*   gt_dst = (const int*)d_in[2];
    const int*   at_src = (const int*)d_in[3];
    const int*   at_dst = (const int*)d_in[4];
    const float* W1     = (const float*)d_in[5];
    const float* b1     = (const float*)d_in[6];
    const float* W2     = (const float*)d_in[7];
    const float* b2     = (const float*)d_in[8];
    const float* W3     = (const float*)d_in[9];
    const float* b3     = (const float*)d_in[10];
    const float* fW1    = (const float*)d_in[11];
    const float* fb1    = (const float*)d_in[12];
    const float* fW2    = (const float*)d_in[13];
    const float* fb2    = (const float*)d_in[14];
    const float* ln_g   = (const float*)d_in[15];
    const float* ln_b   = (const float*)d_in[16];

    const int E = in_sizes[1];
    const int N = in_sizes[0] / DD;
    const size_t NB = (size_t)N * DD;
    const int N2 = 2 * N;
    const int Btot = (N2 + BWIDTH - 1) >> BSH;
    const int n1 = 2 * Btot * NBLK1;

    // ---- workspace layout (combined bf16 tables) ----
    unsigned short* hb   = (unsigned short*)d_ws;          // NB bf16 (12.8 MB)
    unsigned short* bufA = hb + NB;                        // 2*NB bf16 (25.6 MB); -> Qb after stage 3
    unsigned short* bufB = bufA + 2 * NB;                  // 2*NB bf16 (25.6 MB)
    float* sm = (float*)(bufB + 2 * NB);
    float* norms = sm;  sm += N2;
    float* indeg = sm;  sm += N2;
    float* ssum  = sm;  sm += N2;
    float* Tm    = sm;  sm += (size_t)NHEAD * DD * DH;
    float* cvec  = sm;  sm += NHEAD * DH + 32;
    unsigned short* Mtb  = (unsigned short*)sm;
    unsigned short* W1tb = Mtb + DD * DD;
    unsigned short* W2tb = W1tb + DD * DD;
    int* ip = (int*)(W2tb + DD * DD);
    int* rowptr = ip;  ip += ((N2 + 1 + 3) & ~3);
    int* csr    = ip;  ip += 2 * E;
    int* blkcnt = ip;  ip += ((n1 + 1 + 3) & ~3);
    int* scn    = ip;  ip += ((n1 + 1 + 3) & ~3);
    int* part   = ip;  ip += 256;
    // CSR-build scratch aliased over bufA (14.4 MB < 25.6 MB; bufA first written at stage 1)
    int2* pairs = (int2*)bufA;
    int*  svals = (int*)(pairs + 2 * E);
    unsigned short* Qb = bufA;                             // stage-3 output (combined)

    // weight pre-combination / transposed bf16 weights
    k_wcomb  <<<NHEAD, 256, 0, stream>>>(W2, W3, Tm);
    k_wcombTB<<<NHEAD, 256, 0, stream>>>(W1, Tm, Mtb);
    k_cvec   <<<1, 128, 0, stream>>>(b1, b2, Tm, W3, cvec);
    k_wtb    <<<64, 256, 0, stream>>>(fW1, W1tb);
    k_wtb    <<<64, 256, 0, stream>>>(fW2, W2tb);

    const int TB = 256;
    // h -> bf16
    k_h2b<<<(int)(NB / 4 + TB - 1) / TB, TB, 0, stream>>>((const float4*)h, (ushort4*)hb,
                                                          (int)(NB / 4));
    // CSR build (no global atomics)
    k_p1count<<<NBLK1, 256, 0, stream>>>(gt_src, gt_dst, at_src, at_dst, blkcnt, E, N, Btot);
    int nsb = (n1 + 1023) / 1024;
    k_scan1<<<nsb, 256, 0, stream>>>(blkcnt, scn, part, n1);
    k_scan2<<<1, 256, 0, stream>>>(part, nsb);
    k_scan3<<<(n1 + TB - 1) / TB, TB, 0, stream>>>(scn, part, n1, 4 * E);
    k_p1scatter<<<NBLK1, 256, 0, stream>>>(gt_src, gt_dst, at_src, at_dst, scn,
                                           pairs, svals, E, N, Btot);
    k_p2<<<Btot, 256, 0, stream>>>(pairs, svals, scn, rowptr, csr, indeg, norms,
                                   E, N2, Btot);

    // fused pull stages over combined [0,2N): 3 launches
    const int pgrid2 = (N2 + 7) / 8;
    k_pull_avgF<<<pgrid2, 256, 0, stream>>>((const ushort4*)hb, rowptr, csr, norms,
                                            (ushort4*)bufB, N, 1, 0);
    k_pull_avgF<<<pgrid2, 256, 0, stream>>>((const ushort4*)bufB, rowptr, csr, norms,
                                            (ushort4*)bufA, N, 0, 1);
    // note: stage2 wrote bufA (over the now-dead pairs/svals); stage3 reads bufA, writes bufB
    k_pull3F<<<pgrid2, 256, 0, stream>>>((const ushort4*)bufA, rowptr, csr, norms,
                                         (ushort4*)bufB, ssum, N);
    Qb = bufB;

    // fused dense tail (MFMA bf16, 64 rows/block, 256 threads)
    k_tailm<<<(N + 63) / 64, 256, 0, stream>>>(Qb, Qb + NB, ssum, indeg, Mtb, W1tb, W2tb,
                                               cvec, b3, h, ln_g, ln_b, fb1, fb2,
                                               (float*)d_out, N);
}

// Round 13
// 290.014 us; speedup vs baseline: 1.3876x; 1.0923x over previous
//
#include <hip/hip_runtime.h>

#define DD 128
#define NHEAD 8
#define DH 16
#define EPS 1e-5f
#define BSH 9                 // bucket width 512 nodes
#define BWIDTH 512
#define NBLK1 256             // pass-1 blocks

typedef __attribute__((ext_vector_type(8))) short bf16x8;   // 8 bf16 = 4 VGPR
typedef __attribute__((ext_vector_type(4))) float f32x4;

// ---------- bf16 helpers (OCP bf16 = f32 upper half, RNE) ----------
__device__ inline unsigned short f2b(float f) {
    unsigned u = __float_as_uint(f);
    u += 0x7fffu + ((u >> 16) & 1);
    return (unsigned short)(u >> 16);
}
__device__ inline unsigned pk2(float lo, float hi) {
    return (unsigned)f2b(lo) | ((unsigned)f2b(hi) << 16);
}
// unpack-accumulate 8 bf16 (uint4 = 16 B) into a[8]
__device__ inline void upacc(uint4 u, float* a) {
    a[0] += __uint_as_float(u.x << 16);
    a[1] += __uint_as_float(u.x & 0xffff0000u);
    a[2] += __uint_as_float(u.y << 16);
    a[3] += __uint_as_float(u.y & 0xffff0000u);
    a[4] += __uint_as_float(u.z << 16);
    a[5] += __uint_as_float(u.z & 0xffff0000u);
    a[6] += __uint_as_float(u.w << 16);
    a[7] += __uint_as_float(u.w & 0xffff0000u);
}

// XOR swizzle for bf16 MFMA panels (row stride 256 B): keeps 16B alignment.
#define SWZB(row, off) ((off) ^ (((row) & 7) << 4))

// ================= h -> bf16 copy =================
__global__ void k_h2b(const float4* __restrict__ h4, ushort4* __restrict__ hb, int n4) {
    int i = blockIdx.x * 256 + threadIdx.x;
    if (i < n4) {
        float4 v = h4[i];
        hb[i] = make_ushort4(f2b(v.x), f2b(v.y), f2b(v.z), f2b(v.w));
    }
}

// ================= pass 1a: per-block bucket histograms =================
__global__ __launch_bounds__(256) void k_p1count(
        const int* __restrict__ gs, const int* __restrict__ gd,
        const int* __restrict__ as_, const int* __restrict__ ad,
        int* __restrict__ blkcnt, int E, int N, int Btot) {
    __shared__ int cnts[512];
    for (int j = threadIdx.x; j < 2 * Btot; j += 256) cnts[j] = 0;
    __syncthreads();
    int E2 = 2 * E;
    for (int i = blockIdx.x * 256 + threadIdx.x; i < E2; i += NBLK1 * 256) {
        int g = (i >= E);
        int e = g ? i - E : i;
        int s = g ? as_[e] : gs[e];
        int d = g ? ad[e] : gd[e];
        int cd = d + g * N, cs = s + g * N;
        atomicAdd(&cnts[cd >> BSH], 1);
        atomicAdd(&cnts[Btot + (cs >> BSH)], 1);
    }
    __syncthreads();
    for (int j = threadIdx.x; j < 2 * Btot; j += 256)
        blkcnt[j * NBLK1 + blockIdx.x] = cnts[j];
}

// ================= 3-stage scan =================
__global__ void k_scan1(const int* __restrict__ cnt, int* __restrict__ outv,
                        int* __restrict__ part, int n) {
    __shared__ int wsums[4];
    int t = threadIdx.x;
    int base = blockIdx.x * 1024 + t * 4;
    int v0 = 0, v1 = 0, v2 = 0, v3 = 0;
    if (base + 3 < n) {
        int4 q = *(const int4*)(cnt + base);
        v0 = q.x; v1 = q.y; v2 = q.z; v3 = q.w;
    } else {
        if (base < n)     v0 = cnt[base];
        if (base + 1 < n) v1 = cnt[base + 1];
        if (base + 2 < n) v2 = cnt[base + 2];
        if (base + 3 < n) v3 = cnt[base + 3];
    }
    int s0 = v0, s1 = s0 + v1, s2 = s1 + v2, s3 = s2 + v3;
    int x = s3;
    int lane = t & 63, w = t >> 6;
    for (int o = 1; o < 64; o <<= 1) { int u = __shfl_up(x, o); if (lane >= o) x += u; }
    if (lane == 63) wsums[w] = x;
    __syncthreads();
    int wo = 0;
    for (int i = 0; i < w; ++i) wo += wsums[i];
    int excl = wo + x - s3;
    if (base < n)     outv[base]     = excl;
    if (base + 1 < n) outv[base + 1] = excl + s0;
    if (base + 2 < n) outv[base + 2] = excl + s1;
    if (base + 3 < n) outv[base + 3] = excl + s2;
    if (t == 255) part[blockIdx.x] = wo + x;
}

__global__ void k_scan2(int* __restrict__ part, int nb) {
    __shared__ int ws[4];
    int t = threadIdx.x;
    int v = (t < nb) ? part[t] : 0;
    int x = v;
    int lane = t & 63, w = t >> 6;
    for (int o = 1; o < 64; o <<= 1) { int u = __shfl_up(x, o); if (lane >= o) x += u; }
    if (lane == 63) ws[w] = x;
    __syncthreads();
    int wo = 0;
    for (int i = 0; i < w; ++i) wo += ws[i];
    if (t < nb) part[t] = wo + x - v;
}

__global__ void k_scan3(int* __restrict__ outv, const int* __restrict__ part, int n, int total) {
    int i = blockIdx.x * blockDim.x + threadIdx.x;
    if (i < n) outv[i] += part[i >> 10];
    if (i == 0) outv[n] = total;
}

// ================= pass 1b: scatter edges into bucket regions =================
__global__ __launch_bounds__(256) void k_p1scatter(
        const int* __restrict__ gs, const int* __restrict__ gd,
        const int* __restrict__ as_, const int* __restrict__ ad,
        const int* __restrict__ scn, int2* __restrict__ pairs, int* __restrict__ svals,
        int E, int N, int Btot) {
    __shared__ int cur[512];
    for (int j = threadIdx.x; j < 2 * Btot; j += 256)
        cur[j] = scn[j * NBLK1 + blockIdx.x];
    __syncthreads();
    int E2 = 2 * E;
    for (int i = blockIdx.x * 256 + threadIdx.x; i < E2; i += NBLK1 * 256) {
        int g = (i >= E);
        int e = g ? i - E : i;
        int s = g ? as_[e] : gs[e];
        int d = g ? ad[e] : gd[e];
        int cd = d + g * N, cs = s + g * N;
        int pd = atomicAdd(&cur[cd >> BSH], 1);
        pairs[pd] = make_int2(cd, s);
        int ps = atomicAdd(&cur[Btot + (cs >> BSH)], 1);
        svals[ps - E2] = cs;
    }
}

// ================= pass 2: per-bucket CSR + indeg + norms =================
__global__ __launch_bounds__(256) void k_p2(
        const int2* __restrict__ pairs, const int* __restrict__ svals,
        const int* __restrict__ scn, int* __restrict__ rowptr, int* __restrict__ csr,
        float* __restrict__ indeg, float* __restrict__ norms,
        int E, int N2, int Btot) {
    __shared__ int hist[BWIDTH];
    __shared__ int offs[BWIDTH];
    __shared__ int cur[BWIDTH];
    __shared__ int ws4[4];
    int b = blockIdx.x, t = threadIdx.x;
    int node0 = b << BSH;
    int W = N2 - node0; if (W > BWIDTH) W = BWIDTH;
    int Sd = scn[b * NBLK1], Ed = scn[(b + 1) * NBLK1];
    hist[t] = 0; hist[t + 256] = 0;
    __syncthreads();
    for (int i = Sd + t; i < Ed; i += 256) {
        int2 p = pairs[i];
        atomicAdd(&hist[p.x - node0], 1);
    }
    __syncthreads();
    int a0 = hist[2 * t], a1 = hist[2 * t + 1];
    int sum2 = a0 + a1;
    int lane = t & 63, w = t >> 6;
    int x = sum2;
    for (int o = 1; o < 64; o <<= 1) { int u = __shfl_up(x, o); if (lane >= o) x += u; }
    if (lane == 63) ws4[w] = x;
    __syncthreads();
    int wo = 0;
    for (int i = 0; i < w; ++i) wo += ws4[i];
    int excl2 = wo + x - sum2;
    offs[2 * t] = excl2; offs[2 * t + 1] = excl2 + a0;
    cur[t] = 0; cur[t + 256] = 0;
    __syncthreads();
    for (int j = t; j < W; j += 256) {
        rowptr[node0 + j] = Sd + offs[j];
        indeg[node0 + j] = (float)hist[j];
    }
    if (b == 0 && t == 0) rowptr[N2] = 2 * E;
    for (int i = Sd + t; i < Ed; i += 256) {
        int2 p = pairs[i];
        int l = p.x - node0;
        int pos = atomicAdd(&cur[l], 1);
        csr[Sd + offs[l] + pos] = p.y;
    }
    __syncthreads();
    hist[t] = 0; hist[t + 256] = 0;
    __syncthreads();
    int Ss = scn[(Btot + b) * NBLK1] - 2 * E;
    int Es = scn[(Btot + b + 1) * NBLK1] - 2 * E;
    for (int i = Ss + t; i < Es; i += 256)
        atomicAdd(&hist[svals[i] - node0], 1);
    __syncthreads();
    for (int j = t; j < W; j += 256) {
        int od = hist[j];
        norms[node0 + j] = od > 0 ? rsqrtf((float)od) : 0.f;
    }
}

// ======== fused pull stage 1/2: avg (SAGE); 16 lanes/row, uint4 loads ========
// shared_in=1: table rows [0,N) (stage 1, input hb); shared_in=0: combined [0,2N).
// doscale=1 (stage 2): scale output by norms[cd] AND emit ssum[cd] = sum norms[s].
__global__ __launch_bounds__(256) void k_pull_avgF(
        const uint4* __restrict__ xb, const int* __restrict__ rowptr,
        const int* __restrict__ csr, const float* __restrict__ norms,
        uint4* __restrict__ outb, float* __restrict__ ssum,
        int N, int shared_in, int doscale) {
    int cd = blockIdx.x * 16 + (threadIdx.x >> 4);
    int lane = threadIdx.x & 15;
    if (cd >= 2 * N) return;
    int gofs = (cd >= N) ? N : 0;
    int base = shared_in ? 0 : gofs;
    int beg = rowptr[cd], end = rowptr[cd + 1];
    float a[8];
    {
        uint4 u = xb[(size_t)(base + cd - gofs) * 16 + lane];   // self term
        a[0] = __uint_as_float(u.x << 16); a[1] = __uint_as_float(u.x & 0xffff0000u);
        a[2] = __uint_as_float(u.y << 16); a[3] = __uint_as_float(u.y & 0xffff0000u);
        a[4] = __uint_as_float(u.z << 16); a[5] = __uint_as_float(u.z & 0xffff0000u);
        a[6] = __uint_as_float(u.w << 16); a[7] = __uint_as_float(u.w & 0xffff0000u);
    }
    float ss = 0.f;
    int e = beg;
    int nb = end - e; if (nb > 16) nb = 16;
    int idx = (lane < nb) ? csr[e + lane] : 0;
    while (nb > 0) {
        int en = e + nb;
        int nbn = end - en; if (nbn > 16) nbn = 16;
        int idxn = (lane < nbn) ? csr[en + lane] : 0;           // prefetch next chunk
        #pragma unroll 8
        for (int d = 0; d < nb; ++d) {
            int s = __shfl(idx, d, 16);
            upacc(xb[(size_t)(base + s) * 16 + lane], a);
            if (doscale) ss += norms[base + s];
        }
        e = en; nb = nbn; idx = idxn;
    }
    float sc = 1.f / (float)(end - beg + 1);
    if (doscale) sc *= norms[cd];
    uint4 o;
    o.x = pk2(a[0] * sc, a[1] * sc); o.y = pk2(a[2] * sc, a[3] * sc);
    o.z = pk2(a[4] * sc, a[5] * sc); o.w = pk2(a[6] * sc, a[7] * sc);
    outb[(size_t)cd * 16 + lane] = o;
    if (doscale && lane == 0) ssum[cd] = ss;
}

// ======== fused pull stage 3: plain sum of pre-scaled rows -> bf16 Q (combined) ========
__global__ __launch_bounds__(256) void k_pull_sumF(
        const uint4* __restrict__ Pb, const int* __restrict__ rowptr,
        const int* __restrict__ csr, uint4* __restrict__ Qb, int N) {
    int cd = blockIdx.x * 16 + (threadIdx.x >> 4);
    int lane = threadIdx.x & 15;
    if (cd >= 2 * N) return;
    int base = (cd >= N) ? N : 0;
    int beg = rowptr[cd], end = rowptr[cd + 1];
    float a[8] = {0.f, 0.f, 0.f, 0.f, 0.f, 0.f, 0.f, 0.f};
    int e = beg;
    int nb = end - e; if (nb > 16) nb = 16;
    int idx = (lane < nb) ? csr[e + lane] : 0;
    while (nb > 0) {
        int en = e + nb;
        int nbn = end - en; if (nbn > 16) nbn = 16;
        int idxn = (lane < nbn) ? csr[en + lane] : 0;
        #pragma unroll 8
        for (int d = 0; d < nb; ++d) {
            int s = __shfl(idx, d, 16);
            upacc(Pb[(size_t)(base + s) * 16 + lane], a);
        }
        e = en; nb = nbn; idx = idxn;
    }
    uint4 o;
    o.x = pk2(a[0], a[1]); o.y = pk2(a[2], a[3]);
    o.z = pk2(a[4], a[5]); o.w = pk2(a[6], a[7]);
    Qb[(size_t)cd * 16 + lane] = o;
}

// ================= weight pre-combination =================
__global__ void k_wcomb(const float* __restrict__ A, const float* __restrict__ B,
                        float* __restrict__ C) {          // C[i] = A[i](128x128) @ B[i](128x16)
    int i = blockIdx.x;
    const float* Ai = A + (size_t)i * DD * DD;
    const float* Bi = B + (size_t)i * DD * DH;
    float* Ci = C + (size_t)i * DD * DH;
    for (int o = threadIdx.x; o < DD * DH; o += blockDim.x) {
        int r = o >> 4, c = o & 15;
        float acc = 0.f;
        #pragma unroll 8
        for (int k = 0; k < DD; ++k) acc += Ai[r * DD + k] * Bi[k * DH + c];
        Ci[o] = acc;
    }
}

// combined M = W1@T, written TRANSPOSED in bf16: Mtb[(head*16+c)*128 + k]
__global__ void k_wcombTB(const float* __restrict__ A, const float* __restrict__ B,
                          unsigned short* __restrict__ Mtb) {
    int i = blockIdx.x;
    const float* Ai = A + (size_t)i * DD * DD;
    const float* Bi = B + (size_t)i * DD * DH;
    for (int o = threadIdx.x; o < DD * DH; o += blockDim.x) {
        int r = o >> 4, c = o & 15;        // r = k index, c = col within head
        float acc = 0.f;
        #pragma unroll 8
        for (int k = 0; k < DD; ++k) acc += Ai[r * DD + k] * Bi[k * DH + c];
        Mtb[(size_t)(i * DH + c) * DD + r] = f2b(acc);
    }
}

// transpose + bf16 a 128x128 f32 weight: Wtb[c*128+k] = bf16(W[k*128+c])
__global__ void k_wtb(const float* __restrict__ W, unsigned short* __restrict__ Wtb) {
    int idx = blockIdx.x * 256 + threadIdx.x;
    if (idx < DD * DD) {
        int c = idx >> 7, k = idx & 127;
        Wtb[c * DD + k] = f2b(W[(size_t)k * DD + c]);
    }
}

__global__ void k_cvec(const float* __restrict__ b1, const float* __restrict__ b2,
                       const float* __restrict__ T, const float* __restrict__ W3,
                       float* __restrict__ cvec) {
    int idx = blockIdx.x * blockDim.x + threadIdx.x;
    if (idx >= NHEAD * DH) return;
    int i = idx >> 4, c = idx & 15;
    float acc = 0.f;
    for (int k = 0; k < DD; ++k)
        acc += b1[i * DD + k] * T[(size_t)i * DD * DH + k * DH + c]
             + b2[i * DD + k] * W3[(size_t)i * DD * DH + k * DH + c];
    cvec[idx] = acc;
}

// ================= fused tail, MFMA bf16: 64 rows/block, 4 waves =================
__global__ __launch_bounds__(256) void k_tailm(
        const unsigned short* __restrict__ Qgtb, const unsigned short* __restrict__ Qatb,
        const float* __restrict__ ssum, const float* __restrict__ indeg,
        const unsigned short* __restrict__ Mtb, const unsigned short* __restrict__ W1tb,
        const unsigned short* __restrict__ W2tb,
        const float* __restrict__ cvec, const float* __restrict__ b3,
        const float* __restrict__ h, const float* __restrict__ ln_g,
        const float* __restrict__ ln_b, const float* __restrict__ Fb1,
        const float* __restrict__ Fb2, float* __restrict__ out, int N) {
    __shared__ __align__(16) unsigned short A0[64 * DD];   // 16 KB: Qgt -> x panel
    __shared__ __align__(16) unsigned short A1[64 * DD];   // 16 KB: Qat -> f1 panel
    __shared__ __align__(16) unsigned short Bt[DD * DD];   // 32 KB: weight panel [col][k]
    int t = threadIdx.x;
    int w = t >> 6, l = t & 63;
    int lm = l & 15, lk = l >> 4;
    int row0 = blockIdx.x * 64;

    // ---- stage A panels (Q bf16, swizzled) ----
    for (int i = t; i < 1024; i += 256) {
        int r = i >> 4, ch = i & 15;
        int gr = row0 + r; if (gr >= N) gr = N - 1;
        uint4 v0 = *(const uint4*)(Qgtb + (size_t)gr * DD + ch * 8);
        uint4 v1 = *(const uint4*)(Qatb + (size_t)gr * DD + ch * 8);
        *(uint4*)((char*)A0 + r * 256 + SWZB(r, ch * 16)) = v0;
        *(uint4*)((char*)A1 + r * 256 + SWZB(r, ch * 16)) = v1;
    }
    // ---- stage Bt = Mtb ----
    for (int i = t; i < 2048; i += 256) {
        int c = i >> 4, ch = i & 15;
        uint4 v = *(const uint4*)(Mtb + (size_t)c * DD + ch * 8);
        *(uint4*)((char*)Bt + c * 256 + SWZB(c, ch * 16)) = v;
    }
    __syncthreads();

    int arow = w * 16 + lm;
    int abase = arow * 256;

    // ---- GEMM1 ----
    f32x4 acc[8];
    #pragma unroll
    for (int i = 0; i < 8; ++i) acc[i] = (f32x4){0.f, 0.f, 0.f, 0.f};
    #pragma unroll
    for (int kt = 0; kt < 4; ++kt) {
        int aoff = abase + SWZB(arow, kt * 64 + lk * 16);
        bf16x8 ag = *(const bf16x8*)((const char*)A0 + aoff);
        bf16x8 aa = *(const bf16x8*)((const char*)A1 + aoff);
        #pragma unroll
        for (int ct = 0; ct < 8; ++ct) {
            int bc = ct * 16 + lm;
            bf16x8 b = *(const bf16x8*)((const char*)Bt + bc * 256 + SWZB(bc, kt * 64 + lk * 16));
            acc[ct] = __builtin_amdgcn_mfma_f32_16x16x32_bf16(
                ((ct >> 1) & 1) ? aa : ag, b, acc[ct], 0, 0, 0);
        }
    }

    // ---- epilogue 1: (acc + ss*c)*nd + b3, LN over 128 cols, + h residual ----
    int rbase = row0 + w * 16 + lk * 4;
    float ssv[2][4], ndv[2][4];
    #pragma unroll
    for (int i = 0; i < 4; ++i) {
        int rc = rbase + i; if (rc >= N) rc = N - 1;
        #pragma unroll
        for (int g2 = 0; g2 < 2; ++g2) {
            ssv[g2][i] = ssum[g2 * N + rc];
            float id = indeg[g2 * N + rc];
            ndv[g2][i] = id > 0.f ? rsqrtf(id) : 0.f;
        }
    }
    float glr[8], blr[8];
    #pragma unroll
    for (int ct = 0; ct < 8; ++ct) {
        glr[ct] = ln_g[ct * 16 + lm];
        blr[ct] = ln_b[ct * 16 + lm];
    }
    float vv[8][4];
    float s[4] = {0, 0, 0, 0}, s2[4] = {0, 0, 0, 0};
    #pragma unroll
    for (int ct = 0; ct < 8; ++ct) {
        int col = ct * 16 + lm;
        int g2 = (ct >> 1) & 1;
        float cvv = cvec[col], b3v = b3[col];
        #pragma unroll
        for (int i = 0; i < 4; ++i) {
            float v = (acc[ct][i] + ssv[g2][i] * cvv) * ndv[g2][i] + b3v;
            vv[ct][i] = v;
            s[i] += v; s2[i] += v * v;
        }
    }
    #pragma unroll
    for (int o = 8; o > 0; o >>= 1) {
        #pragma unroll
        for (int i = 0; i < 4; ++i) {
            s[i] += __shfl_xor(s[i], o);
            s2[i] += __shfl_xor(s2[i], o);
        }
    }
    __syncthreads();                        // all GEMM1 LDS reads done
    float xk[8][4];
    #pragma unroll
    for (int i = 0; i < 4; ++i) {
        float mu = s[i] * (1.f / DD);
        float var = s2[i] * (1.f / DD) - mu * mu;
        float rs = rsqrtf(var + EPS);
        int row = rbase + i; int rc = row < N ? row : N - 1;
        int lrow = w * 16 + lk * 4 + i;
        #pragma unroll
        for (int ct = 0; ct < 8; ++ct) {
            int col = ct * 16 + lm;
            float x = h[(size_t)rc * DD + col] + (vv[ct][i] - mu) * rs * glr[ct] + blr[ct];
            xk[ct][i] = x;
            *(unsigned short*)((char*)A0 + lrow * 256 + SWZB(lrow, 2 * col)) = f2b(x);
        }
    }
    for (int i = t; i < 2048; i += 256) {   // stage Bt = W1tb
        int c = i >> 4, ch = i & 15;
        uint4 v = *(const uint4*)(W1tb + (size_t)c * DD + ch * 8);
        *(uint4*)((char*)Bt + c * 256 + SWZB(c, ch * 16)) = v;
    }
    __syncthreads();

    // ---- GEMM2: f1 = relu(x @ fW1 + Fb1) ----
    f32x4 ac2[8];
    #pragma unroll
    for (int i = 0; i < 8; ++i) ac2[i] = (f32x4){0.f, 0.f, 0.f, 0.f};
    #pragma unroll
    for (int kt = 0; kt < 4; ++kt) {
        bf16x8 a = *(const bf16x8*)((const char*)A0 + abase + SWZB(arow, kt * 64 + lk * 16));
        #pragma unroll
        for (int ct = 0; ct < 8; ++ct) {
            int bc = ct * 16 + lm;
            bf16x8 b = *(const bf16x8*)((const char*)Bt + bc * 256 + SWZB(bc, kt * 64 + lk * 16));
            ac2[ct] = __builtin_amdgcn_mfma_f32_16x16x32_bf16(a, b, ac2[ct], 0, 0, 0);
        }
    }
    #pragma unroll
    for (int i = 0; i < 4; ++i) {
        int lrow = w * 16 + lk * 4 + i;
        #pragma unroll
        for (int ct = 0; ct < 8; ++ct) {
            int col = ct * 16 + lm;
            float f = ac2[ct][i] + Fb1[col];
            *(unsigned short*)((char*)A1 + lrow * 256 + SWZB(lrow, 2 * col)) =
                f2b(f > 0.f ? f : 0.f);
        }
    }
    __syncthreads();                        // GEMM2 Bt reads + f1 writes done
    for (int i = t; i < 2048; i += 256) {   // stage Bt = W2tb
        int c = i >> 4, ch = i & 15;
        uint4 v = *(const uint4*)(W2tb + (size_t)c * DD + ch * 8);
        *(uint4*)((char*)Bt + c * 256 + SWZB(c, ch * 16)) = v;
    }
    __syncthreads();

    // ---- GEMM3: out = x + LN(f1 @ fW2 + Fb2) ----
    f32x4 ac3[8];
    #pragma unroll
    for (int i = 0; i < 8; ++i) ac3[i] = (f32x4){0.f, 0.f, 0.f, 0.f};
    #pragma unroll
    for (int kt = 0; kt < 4; ++kt) {
        bf16x8 a = *(const bf16x8*)((const char*)A1 + abase + SWZB(arow, kt * 64 + lk * 16));
        #pragma unroll
        for (int ct = 0; ct < 8; ++ct) {
            int bc = ct * 16 + lm;
            bf16x8 b = *(const bf16x8*)((const char*)Bt + bc * 256 + SWZB(bc, kt * 64 + lk * 16));
            ac3[ct] = __builtin_amdgcn_mfma_f32_16x16x32_bf16(a, b, ac3[ct], 0, 0, 0);
        }
    }
    float v3[8][4];
    float s3[4] = {0, 0, 0, 0}, s32[4] = {0, 0, 0, 0};
    #pragma unroll
    for (int ct = 0; ct < 8; ++ct) {
        float fb = Fb2[ct * 16 + lm];
        #pragma unroll
        for (int i = 0; i < 4; ++i) {
            float v = ac3[ct][i] + fb;
            v3[ct][i] = v;
            s3[i] += v; s32[i] += v * v;
        }
    }
    #pragma unroll
    for (int o = 8; o > 0; o >>= 1) {
        #pragma unroll
        for (int i = 0; i < 4; ++i) {
            s3[i] += __shfl_xor(s3[i], o);
            s32[i] += __shfl_xor(s32[i], o);
        }
    }
    #pragma unroll
    for (int i = 0; i < 4; ++i) {
        float mu = s3[i] * (1.f / DD);
        float var = s32[i] * (1.f / DD) - mu * mu;
        float rs = rsqrtf(var + EPS);
        int row = rbase + i;
        if (row < N) {
            #pragma unroll
            for (int ct = 0; ct < 8; ++ct) {
                int col = ct * 16 + lm;
                out[(size_t)row * DD + col] = xk[ct][i] + (v3[ct][i] - mu) * rs * glr[ct] + blr[ct];
            }
        }
    }
}

extern "C" void kernel_launch(void* const* d_in, const int* in_sizes, int n_in,
                              void* d_out, int out_size, void* d_ws, size_t ws_size,
                              hipStream_t stream) {
    const float* h      = (const float*)d_in[0];
    const int*   gt_src = (const int*)d_in[1];
    const int*   gt_dst = (const int*)d_in[2];
    const int*   at_src = (const int*)d_in[3];
    const int*   at_dst = (const int*)d_in[4];
    const float* W1     = (const float*)d_in[5];
    const float* b1     = (const float*)d_in[6];
    const float* W2     = (const float*)d_in[7];
    const float* b2     = (const float*)d_in[8];
    const float* W3     = (const float*)d_in[9];
    const float* b3     = (const float*)d_in[10];
    const float* fW1    = (const float*)d_in[11];
    const float* fb1    = (const float*)d_in[12];
    const float* fW2    = (const float*)d_in[13];
    const float* fb2    = (const float*)d_in[14];
    const float* ln_g   = (const float*)d_in[15];
    const float* ln_b   = (const float*)d_in[16];

    const int E = in_sizes[1];
    const int N = in_sizes[0] / DD;
    const size_t NB = (size_t)N * DD;
    const int N2 = 2 * N;
    const int Btot = (N2 + BWIDTH - 1) >> BSH;
    const int n1 = 2 * Btot * NBLK1;

    // ---- workspace layout (combined bf16 tables) ----
    unsigned short* hb   = (unsigned short*)d_ws;          // NB bf16 (12.8 MB)
    unsigned short* bufA = hb + NB;                        // 2*NB bf16 (25.6 MB)
    unsigned short* bufB = bufA + 2 * NB;                  // 2*NB bf16 (25.6 MB)
    float* sm = (float*)(bufB + 2 * NB);
    float* norms = sm;  sm += N2;
    float* indeg = sm;  sm += N2;
    float* ssum  = sm;  sm += N2;
    float* Tm    = sm;  sm += (size_t)NHEAD * DD * DH;
    float* cvec  = sm;  sm += NHEAD * DH + 32;
    unsigned short* Mtb  = (unsigned short*)sm;
    unsigned short* W1tb = Mtb + DD * DD;
    unsigned short* W2tb = W1tb + DD * DD;
    int* ip = (int*)(W2tb + DD * DD);
    int* rowptr = ip;  ip += ((N2 + 1 + 3) & ~3);
    int* csr    = ip;  ip += 2 * E;
    int* blkcnt = ip;  ip += ((n1 + 1 + 3) & ~3);
    int* scn    = ip;  ip += ((n1 + 1 + 3) & ~3);
    int* part   = ip;  ip += 256;
    // CSR-build scratch aliased over bufA (14.4 MB < 25.6 MB; bufA first written at stage 2)
    int2* pairs = (int2*)bufA;
    int*  svals = (int*)(pairs + 2 * E);

    // weight pre-combination / transposed bf16 weights
    k_wcomb  <<<NHEAD, 256, 0, stream>>>(W2, W3, Tm);
    k_wcombTB<<<NHEAD, 256, 0, stream>>>(W1, Tm, Mtb);
    k_cvec   <<<1, 128, 0, stream>>>(b1, b2, Tm, W3, cvec);
    k_wtb    <<<64, 256, 0, stream>>>(fW1, W1tb);
    k_wtb    <<<64, 256, 0, stream>>>(fW2, W2tb);

    const int TB = 256;
    // h -> bf16
    k_h2b<<<(int)(NB / 4 + TB - 1) / TB, TB, 0, stream>>>((const float4*)h, (ushort4*)hb,
                                                          (int)(NB / 4));
    // CSR build (no global atomics)
    k_p1count<<<NBLK1, 256, 0, stream>>>(gt_src, gt_dst, at_src, at_dst, blkcnt, E, N, Btot);
    int nsb = (n1 + 1023) / 1024;
    k_scan1<<<nsb, 256, 0, stream>>>(blkcnt, scn, part, n1);
    k_scan2<<<1, 256, 0, stream>>>(part, nsb);
    k_scan3<<<(n1 + TB - 1) / TB, TB, 0, stream>>>(scn, part, n1, 4 * E);
    k_p1scatter<<<NBLK1, 256, 0, stream>>>(gt_src, gt_dst, at_src, at_dst, scn,
                                           pairs, svals, E, N, Btot);
    k_p2<<<Btot, 256, 0, stream>>>(pairs, svals, scn, rowptr, csr, indeg, norms,
                                   E, N2, Btot);

    // fused pull stages over combined [0,2N): 3 launches, 16 lanes/row uint4
    const int pgrid2 = (N2 + 15) / 16;
    k_pull_avgF<<<pgrid2, 256, 0, stream>>>((const uint4*)hb, rowptr, csr, norms,
                                            (uint4*)bufB, ssum, N, 1, 0);
    k_pull_avgF<<<pgrid2, 256, 0, stream>>>((const uint4*)bufB, rowptr, csr, norms,
                                            (uint4*)bufA, ssum, N, 0, 1);
    k_pull_sumF<<<pgrid2, 256, 0, stream>>>((const uint4*)bufA, rowptr, csr,
                                            (uint4*)bufB, N);
    unsigned short* Qb = bufB;

    // fused dense tail (MFMA bf16, 64 rows/block, 256 threads)
    k_tailm<<<(N + 63) / 64, 256, 0, stream>>>(Qb, Qb + NB, ssum, indeg, Mtb, W1tb, W2tb,
                                               cvec, b3, h, ln_g, ln_b, fb1, fb2,
                                               (float*)d_out, N);
}

// Round 14
// 276.262 us; speedup vs baseline: 1.4566x; 1.0498x over previous
//
#include <hip/hip_runtime.h>

#define DD 128
#define NHEAD 8
#define DH 16
#define EPS 1e-5f
#define BSH 9                 // bucket width 512 nodes
#define BWIDTH 512
#define NBLK1 256             // pass-1 blocks

typedef __attribute__((ext_vector_type(8))) short bf16x8;   // 8 bf16 = 4 VGPR
typedef __attribute__((ext_vector_type(4))) float f32x4;

// ---------- bf16 helpers (OCP bf16 = f32 upper half, RNE) ----------
__device__ inline unsigned short f2b(float f) {
    unsigned u = __float_as_uint(f);
    u += 0x7fffu + ((u >> 16) & 1);
    return (unsigned short)(u >> 16);
}
__device__ inline unsigned pk2(float lo, float hi) {
    return (unsigned)f2b(lo) | ((unsigned)f2b(hi) << 16);
}
// unpack-accumulate 8 bf16 (uint4 = 16 B) into a[8]
__device__ inline void upacc(uint4 u, float* a) {
    a[0] += __uint_as_float(u.x << 16);
    a[1] += __uint_as_float(u.x & 0xffff0000u);
    a[2] += __uint_as_float(u.y << 16);
    a[3] += __uint_as_float(u.y & 0xffff0000u);
    a[4] += __uint_as_float(u.z << 16);
    a[5] += __uint_as_float(u.z & 0xffff0000u);
    a[6] += __uint_as_float(u.w << 16);
    a[7] += __uint_as_float(u.w & 0xffff0000u);
}

// XOR swizzle for bf16 MFMA panels (row stride 256 B): keeps 16B alignment.
#define SWZB(row, off) ((off) ^ (((row) & 7) << 4))

// ================= h -> bf16 copy =================
__global__ void k_h2b(const float4* __restrict__ h4, ushort4* __restrict__ hb, int n4) {
    int i = blockIdx.x * 256 + threadIdx.x;
    if (i < n4) {
        float4 v = h4[i];
        hb[i] = make_ushort4(f2b(v.x), f2b(v.y), f2b(v.z), f2b(v.w));
    }
}

// ================= pass 1a: per-block bucket histograms =================
__global__ __launch_bounds__(256) void k_p1count(
        const int* __restrict__ gs, const int* __restrict__ gd,
        const int* __restrict__ as_, const int* __restrict__ ad,
        int* __restrict__ blkcnt, int E, int N, int Btot) {
    __shared__ int cnts[512];
    for (int j = threadIdx.x; j < 2 * Btot; j += 256) cnts[j] = 0;
    __syncthreads();
    int E2 = 2 * E;
    for (int i = blockIdx.x * 256 + threadIdx.x; i < E2; i += NBLK1 * 256) {
        int g = (i >= E);
        int e = g ? i - E : i;
        int s = g ? as_[e] : gs[e];
        int d = g ? ad[e] : gd[e];
        int cd = d + g * N, cs = s + g * N;
        atomicAdd(&cnts[cd >> BSH], 1);
        atomicAdd(&cnts[Btot + (cs >> BSH)], 1);
    }
    __syncthreads();
    for (int j = threadIdx.x; j < 2 * Btot; j += 256)
        blkcnt[j * NBLK1 + blockIdx.x] = cnts[j];
}

// ================= 3-stage scan =================
__global__ void k_scan1(const int* __restrict__ cnt, int* __restrict__ outv,
                        int* __restrict__ part, int n) {
    __shared__ int wsums[4];
    int t = threadIdx.x;
    int base = blockIdx.x * 1024 + t * 4;
    int v0 = 0, v1 = 0, v2 = 0, v3 = 0;
    if (base + 3 < n) {
        int4 q = *(const int4*)(cnt + base);
        v0 = q.x; v1 = q.y; v2 = q.z; v3 = q.w;
    } else {
        if (base < n)     v0 = cnt[base];
        if (base + 1 < n) v1 = cnt[base + 1];
        if (base + 2 < n) v2 = cnt[base + 2];
        if (base + 3 < n) v3 = cnt[base + 3];
    }
    int s0 = v0, s1 = s0 + v1, s2 = s1 + v2, s3 = s2 + v3;
    int x = s3;
    int lane = t & 63, w = t >> 6;
    for (int o = 1; o < 64; o <<= 1) { int u = __shfl_up(x, o); if (lane >= o) x += u; }
    if (lane == 63) wsums[w] = x;
    __syncthreads();
    int wo = 0;
    for (int i = 0; i < w; ++i) wo += wsums[i];
    int excl = wo + x - s3;
    if (base < n)     outv[base]     = excl;
    if (base + 1 < n) outv[base + 1] = excl + s0;
    if (base + 2 < n) outv[base + 2] = excl + s1;
    if (base + 3 < n) outv[base + 3] = excl + s2;
    if (t == 255) part[blockIdx.x] = wo + x;
}

__global__ void k_scan2(int* __restrict__ part, int nb) {
    __shared__ int ws[4];
    int t = threadIdx.x;
    int v = (t < nb) ? part[t] : 0;
    int x = v;
    int lane = t & 63, w = t >> 6;
    for (int o = 1; o < 64; o <<= 1) { int u = __shfl_up(x, o); if (lane >= o) x += u; }
    if (lane == 63) ws[w] = x;
    __syncthreads();
    int wo = 0;
    for (int i = 0; i < w; ++i) wo += ws[i];
    if (t < nb) part[t] = wo + x - v;
}

__global__ void k_scan3(int* __restrict__ outv, const int* __restrict__ part, int n, int total) {
    int i = blockIdx.x * blockDim.x + threadIdx.x;
    if (i < n) outv[i] += part[i >> 10];
    if (i == 0) outv[n] = total;
}

// ======== pass 1b: scatter edges into bucket regions (packed: local_d<<16 | src) ========
// requires N <= 65536 and BWIDTH <= 512 (src 16 bits, local 9 bits)
__global__ __launch_bounds__(256) void k_p1scatter(
        const int* __restrict__ gs, const int* __restrict__ gd,
        const int* __restrict__ as_, const int* __restrict__ ad,
        const int* __restrict__ scn, unsigned* __restrict__ pairs,
        unsigned short* __restrict__ svals, int E, int N, int Btot) {
    __shared__ int cur[512];
    for (int j = threadIdx.x; j < 2 * Btot; j += 256)
        cur[j] = scn[j * NBLK1 + blockIdx.x];
    __syncthreads();
    int E2 = 2 * E;
    for (int i = blockIdx.x * 256 + threadIdx.x; i < E2; i += NBLK1 * 256) {
        int g = (i >= E);
        int e = g ? i - E : i;
        int s = g ? as_[e] : gs[e];
        int d = g ? ad[e] : gd[e];
        int cd = d + g * N, cs = s + g * N;
        int pd = atomicAdd(&cur[cd >> BSH], 1);
        pairs[pd] = ((unsigned)(cd & (BWIDTH - 1)) << 16) | (unsigned)s;
        int ps = atomicAdd(&cur[Btot + (cs >> BSH)], 1);
        svals[ps - E2] = (unsigned short)(cs & (BWIDTH - 1));
    }
}

// ================= pass 2: per-bucket CSR + indeg + norms =================
__global__ __launch_bounds__(256) void k_p2(
        const unsigned* __restrict__ pairs, const unsigned short* __restrict__ svals,
        const int* __restrict__ scn, int* __restrict__ rowptr, int* __restrict__ csr,
        float* __restrict__ indeg, float* __restrict__ norms,
        int E, int N2, int Btot) {
    __shared__ int hist[BWIDTH];
    __shared__ int offs[BWIDTH];
    __shared__ int cur[BWIDTH];
    __shared__ int ws4[4];
    int b = blockIdx.x, t = threadIdx.x;
    int node0 = b << BSH;
    int W = N2 - node0; if (W > BWIDTH) W = BWIDTH;
    int Sd = scn[b * NBLK1], Ed = scn[(b + 1) * NBLK1];
    hist[t] = 0; hist[t + 256] = 0;
    __syncthreads();
    for (int i = Sd + t; i < Ed; i += 256)
        atomicAdd(&hist[pairs[i] >> 16], 1);
    __syncthreads();
    int a0 = hist[2 * t], a1 = hist[2 * t + 1];
    int sum2 = a0 + a1;
    int lane = t & 63, w = t >> 6;
    int x = sum2;
    for (int o = 1; o < 64; o <<= 1) { int u = __shfl_up(x, o); if (lane >= o) x += u; }
    if (lane == 63) ws4[w] = x;
    __syncthreads();
    int wo = 0;
    for (int i = 0; i < w; ++i) wo += ws4[i];
    int excl2 = wo + x - sum2;
    offs[2 * t] = excl2; offs[2 * t + 1] = excl2 + a0;
    cur[t] = 0; cur[t + 256] = 0;
    __syncthreads();
    for (int j = t; j < W; j += 256) {
        rowptr[node0 + j] = Sd + offs[j];
        indeg[node0 + j] = (float)hist[j];
    }
    if (b == 0 && t == 0) rowptr[N2] = 2 * E;
    for (int i = Sd + t; i < Ed; i += 256) {
        unsigned p = pairs[i];
        int l = p >> 16;
        int pos = atomicAdd(&cur[l], 1);
        csr[Sd + offs[l] + pos] = (int)(p & 0xffffu);
    }
    __syncthreads();
    hist[t] = 0; hist[t + 256] = 0;
    __syncthreads();
    int Ss = scn[(Btot + b) * NBLK1] - 2 * E;
    int Es = scn[(Btot + b + 1) * NBLK1] - 2 * E;
    for (int i = Ss + t; i < Es; i += 256)
        atomicAdd(&hist[svals[i]], 1);
    __syncthreads();
    for (int j = t; j < W; j += 256) {
        int od = hist[j];
        norms[node0 + j] = od > 0 ? rsqrtf((float)od) : 0.f;
    }
}

// ======== fused pull stage 1/2: avg (SAGE); 16 lanes/row, uint4 loads ========
__global__ __launch_bounds__(256) void k_pull_avgF(
        const uint4* __restrict__ xb, const int* __restrict__ rowptr,
        const int* __restrict__ csr, const float* __restrict__ norms,
        uint4* __restrict__ outb, float* __restrict__ ssum,
        int N, int shared_in, int doscale) {
    int cd = blockIdx.x * 16 + (threadIdx.x >> 4);
    int lane = threadIdx.x & 15;
    if (cd >= 2 * N) return;
    int gofs = (cd >= N) ? N : 0;
    int base = shared_in ? 0 : gofs;
    int beg = rowptr[cd], end = rowptr[cd + 1];
    float a[8];
    {
        uint4 u = xb[(size_t)(base + cd - gofs) * 16 + lane];   // self term
        a[0] = __uint_as_float(u.x << 16); a[1] = __uint_as_float(u.x & 0xffff0000u);
        a[2] = __uint_as_float(u.y << 16); a[3] = __uint_as_float(u.y & 0xffff0000u);
        a[4] = __uint_as_float(u.z << 16); a[5] = __uint_as_float(u.z & 0xffff0000u);
        a[6] = __uint_as_float(u.w << 16); a[7] = __uint_as_float(u.w & 0xffff0000u);
    }
    float ss = 0.f;
    int e = beg;
    int nb = end - e; if (nb > 16) nb = 16;
    int idx = (lane < nb) ? csr[e + lane] : 0;
    while (nb > 0) {
        int en = e + nb;
        int nbn = end - en; if (nbn > 16) nbn = 16;
        int idxn = (lane < nbn) ? csr[en + lane] : 0;           // prefetch next chunk
        #pragma unroll 8
        for (int d = 0; d < nb; ++d) {
            int s = __shfl(idx, d, 16);
            upacc(xb[(size_t)(base + s) * 16 + lane], a);
            if (doscale) ss += norms[base + s];
        }
        e = en; nb = nbn; idx = idxn;
    }
    float sc = 1.f / (float)(end - beg + 1);
    if (doscale) sc *= norms[cd];
    uint4 o;
    o.x = pk2(a[0] * sc, a[1] * sc); o.y = pk2(a[2] * sc, a[3] * sc);
    o.z = pk2(a[4] * sc, a[5] * sc); o.w = pk2(a[6] * sc, a[7] * sc);
    outb[(size_t)cd * 16 + lane] = o;
    if (doscale && lane == 0) ssum[cd] = ss;
}

// ======== fused pull stage 3: plain sum of pre-scaled rows -> bf16 Q (combined) ========
__global__ __launch_bounds__(256) void k_pull_sumF(
        const uint4* __restrict__ Pb, const int* __restrict__ rowptr,
        const int* __restrict__ csr, uint4* __restrict__ Qb, int N) {
    int cd = blockIdx.x * 16 + (threadIdx.x >> 4);
    int lane = threadIdx.x & 15;
    if (cd >= 2 * N) return;
    int base = (cd >= N) ? N : 0;
    int beg = rowptr[cd], end = rowptr[cd + 1];
    float a[8] = {0.f, 0.f, 0.f, 0.f, 0.f, 0.f, 0.f, 0.f};
    int e = beg;
    int nb = end - e; if (nb > 16) nb = 16;
    int idx = (lane < nb) ? csr[e + lane] : 0;
    while (nb > 0) {
        int en = e + nb;
        int nbn = end - en; if (nbn > 16) nbn = 16;
        int idxn = (lane < nbn) ? csr[en + lane] : 0;
        #pragma unroll 8
        for (int d = 0; d < nb; ++d) {
            int s = __shfl(idx, d, 16);
            upacc(Pb[(size_t)(base + s) * 16 + lane], a);
        }
        e = en; nb = nbn; idx = idxn;
    }
    uint4 o;
    o.x = pk2(a[0], a[1]); o.y = pk2(a[2], a[3]);
    o.z = pk2(a[4], a[5]); o.w = pk2(a[6], a[7]);
    Qb[(size_t)cd * 16 + lane] = o;
}

// ======== fused weight prep: per head, T = W2@W3 (LDS), Mtb = (W1@T)^T bf16, cvec ========
__global__ __launch_bounds__(256) void k_wprep(
        const float* __restrict__ W1, const float* __restrict__ W2,
        const float* __restrict__ W3, const float* __restrict__ b1,
        const float* __restrict__ b2, unsigned short* __restrict__ Mtb,
        float* __restrict__ cvec) {
    __shared__ float T[DD * DH];
    int i = blockIdx.x, t = threadIdx.x;
    const float* W2i = W2 + (size_t)i * DD * DD;
    const float* W3i = W3 + (size_t)i * DD * DH;
    const float* W1i = W1 + (size_t)i * DD * DD;
    for (int o = t; o < DD * DH; o += 256) {
        int r = o >> 4, c = o & 15;
        float acc = 0.f;
        #pragma unroll 8
        for (int k = 0; k < DD; ++k) acc += W2i[r * DD + k] * W3i[k * DH + c];
        T[o] = acc;
    }
    __syncthreads();
    for (int o = t; o < DD * DH; o += 256) {
        int r = o >> 4, c = o & 15;
        float acc = 0.f;
        #pragma unroll 8
        for (int k = 0; k < DD; ++k) acc += W1i[r * DD + k] * T[k * DH + c];
        Mtb[(size_t)(i * DH + c) * DD + r] = f2b(acc);
    }
    if (t < DH) {
        int c = t;
        float acc = 0.f;
        for (int k = 0; k < DD; ++k)
            acc += b1[i * DD + k] * T[k * DH + c] + b2[i * DD + k] * W3i[k * DH + c];
        cvec[i * DH + c] = acc;
    }
}

// transpose + bf16 both FFN weights in one launch (128 blocks)
__global__ void k_wtb2(const float* __restrict__ fW1, const float* __restrict__ fW2,
                       unsigned short* __restrict__ W1tb, unsigned short* __restrict__ W2tb) {
    int idx = blockIdx.x * 256 + threadIdx.x;      // 32768 total
    int which = idx >> 14;
    int o = idx & 16383;
    int c = o >> 7, k = o & 127;
    const float* W = which ? fW2 : fW1;
    unsigned short* Wt = which ? W2tb : W1tb;
    Wt[c * DD + k] = f2b(W[(size_t)k * DD + c]);
}

// ================= fused tail, MFMA bf16: 64 rows/block, 4 waves =================
__global__ __launch_bounds__(256) void k_tailm(
        const unsigned short* __restrict__ Qgtb, const unsigned short* __restrict__ Qatb,
        const float* __restrict__ ssum, const float* __restrict__ indeg,
        const unsigned short* __restrict__ Mtb, const unsigned short* __restrict__ W1tb,
        const unsigned short* __restrict__ W2tb,
        const float* __restrict__ cvec, const float* __restrict__ b3,
        const float* __restrict__ h, const float* __restrict__ ln_g,
        const float* __restrict__ ln_b, const float* __restrict__ Fb1,
        const float* __restrict__ Fb2, float* __restrict__ out, int N) {
    __shared__ __align__(16) unsigned short A0[64 * DD];   // 16 KB: Qgt -> x panel
    __shared__ __align__(16) unsigned short A1[64 * DD];   // 16 KB: Qat -> f1 panel
    __shared__ __align__(16) unsigned short Bt[DD * DD];   // 32 KB: weight panel [col][k]
    int t = threadIdx.x;
    int w = t >> 6, l = t & 63;
    int lm = l & 15, lk = l >> 4;
    int row0 = blockIdx.x * 64;

    // ---- stage A panels (Q bf16, swizzled) ----
    for (int i = t; i < 1024; i += 256) {
        int r = i >> 4, ch = i & 15;
        int gr = row0 + r; if (gr >= N) gr = N - 1;
        uint4 v0 = *(const uint4*)(Qgtb + (size_t)gr * DD + ch * 8);
        uint4 v1 = *(const uint4*)(Qatb + (size_t)gr * DD + ch * 8);
        *(uint4*)((char*)A0 + r * 256 + SWZB(r, ch * 16)) = v0;
        *(uint4*)((char*)A1 + r * 256 + SWZB(r, ch * 16)) = v1;
    }
    // ---- stage Bt = Mtb ----
    for (int i = t; i < 2048; i += 256) {
        int c = i >> 4, ch = i & 15;
        uint4 v = *(const uint4*)(Mtb + (size_t)c * DD + ch * 8);
        *(uint4*)((char*)Bt + c * 256 + SWZB(c, ch * 16)) = v;
    }
    __syncthreads();

    int arow = w * 16 + lm;
    int abase = arow * 256;

    // ---- GEMM1 ----
    f32x4 acc[8];
    #pragma unroll
    for (int i = 0; i < 8; ++i) acc[i] = (f32x4){0.f, 0.f, 0.f, 0.f};
    #pragma unroll
    for (int kt = 0; kt < 4; ++kt) {
        int aoff = abase + SWZB(arow, kt * 64 + lk * 16);
        bf16x8 ag = *(const bf16x8*)((const char*)A0 + aoff);
        bf16x8 aa = *(const bf16x8*)((const char*)A1 + aoff);
        #pragma unroll
        for (int ct = 0; ct < 8; ++ct) {
            int bc = ct * 16 + lm;
            bf16x8 b = *(const bf16x8*)((const char*)Bt + bc * 256 + SWZB(bc, kt * 64 + lk * 16));
            acc[ct] = __builtin_amdgcn_mfma_f32_16x16x32_bf16(
                ((ct >> 1) & 1) ? aa : ag, b, acc[ct], 0, 0, 0);
        }
    }

    // ---- epilogue 1: (acc + ss*c)*nd + b3, LN over 128 cols, + h residual ----
    int rbase = row0 + w * 16 + lk * 4;
    float ssv[2][4], ndv[2][4];
    #pragma unroll
    for (int i = 0; i < 4; ++i) {
        int rc = rbase + i; if (rc >= N) rc = N - 1;
        #pragma unroll
        for (int g2 = 0; g2 < 2; ++g2) {
            ssv[g2][i] = ssum[g2 * N + rc];
            float id = indeg[g2 * N + rc];
            ndv[g2][i] = id > 0.f ? rsqrtf(id) : 0.f;
        }
    }
    float glr[8], blr[8];
    #pragma unroll
    for (int ct = 0; ct < 8; ++ct) {
        glr[ct] = ln_g[ct * 16 + lm];
        blr[ct] = ln_b[ct * 16 + lm];
    }
    float vv[8][4];
    float s[4] = {0, 0, 0, 0}, s2[4] = {0, 0, 0, 0};
    #pragma unroll
    for (int ct = 0; ct < 8; ++ct) {
        int col = ct * 16 + lm;
        int g2 = (ct >> 1) & 1;
        float cvv = cvec[col], b3v = b3[col];
        #pragma unroll
        for (int i = 0; i < 4; ++i) {
            float v = (acc[ct][i] + ssv[g2][i] * cvv) * ndv[g2][i] + b3v;
            vv[ct][i] = v;
            s[i] += v; s2[i] += v * v;
        }
    }
    #pragma unroll
    for (int o = 8; o > 0; o >>= 1) {
        #pragma unroll
        for (int i = 0; i < 4; ++i) {
            s[i] += __shfl_xor(s[i], o);
            s2[i] += __shfl_xor(s2[i], o);
        }
    }
    __syncthreads();                        // all GEMM1 LDS reads done
    float xk[8][4];
    #pragma unroll
    for (int i = 0; i < 4; ++i) {
        float mu = s[i] * (1.f / DD);
        float var = s2[i] * (1.f / DD) - mu * mu;
        float rs = rsqrtf(var + EPS);
        int row = rbase + i; int rc = row < N ? row : N - 1;
        int lrow = w * 16 + lk * 4 + i;
        #pragma unroll
        for (int ct = 0; ct < 8; ++ct) {
            int col = ct * 16 + lm;
            float x = h[(size_t)rc * DD + col] + (vv[ct][i] - mu) * rs * glr[ct] + blr[ct];
            xk[ct][i] = x;
            *(unsigned short*)((char*)A0 + lrow * 256 + SWZB(lrow, 2 * col)) = f2b(x);
        }
    }
    for (int i = t; i < 2048; i += 256) {   // stage Bt = W1tb
        int c = i >> 4, ch = i & 15;
        uint4 v = *(const uint4*)(W1tb + (size_t)c * DD + ch * 8);
        *(uint4*)((char*)Bt + c * 256 + SWZB(c, ch * 16)) = v;
    }
    __syncthreads();

    // ---- GEMM2: f1 = relu(x @ fW1 + Fb1) ----
    f32x4 ac2[8];
    #pragma unroll
    for (int i = 0; i < 8; ++i) ac2[i] = (f32x4){0.f, 0.f, 0.f, 0.f};
    #pragma unroll
    for (int kt = 0; kt < 4; ++kt) {
        bf16x8 a = *(const bf16x8*)((const char*)A0 + abase + SWZB(arow, kt * 64 + lk * 16));
        #pragma unroll
        for (int ct = 0; ct < 8; ++ct) {
            int bc = ct * 16 + lm;
            bf16x8 b = *(const bf16x8*)((const char*)Bt + bc * 256 + SWZB(bc, kt * 64 + lk * 16));
            ac2[ct] = __builtin_amdgcn_mfma_f32_16x16x32_bf16(a, b, ac2[ct], 0, 0, 0);
        }
    }
    #pragma unroll
    for (int i = 0; i < 4; ++i) {
        int lrow = w * 16 + lk * 4 + i;
        #pragma unroll
        for (int ct = 0; ct < 8; ++ct) {
            int col = ct * 16 + lm;
            float f = ac2[ct][i] + Fb1[col];
            *(unsigned short*)((char*)A1 + lrow * 256 + SWZB(lrow, 2 * col)) =
                f2b(f > 0.f ? f : 0.f);
        }
    }
    __syncthreads();                        // GEMM2 Bt reads + f1 writes done
    for (int i = t; i < 2048; i += 256) {   // stage Bt = W2tb
        int c = i >> 4, ch = i & 15;
        uint4 v = *(const uint4*)(W2tb + (size_t)c * DD + ch * 8);
        *(uint4*)((char*)Bt + c * 256 + SWZB(c, ch * 16)) = v;
    }
    __syncthreads();

    // ---- GEMM3: out = x + LN(f1 @ fW2 + Fb2) ----
    f32x4 ac3[8];
    #pragma unroll
    for (int i = 0; i < 8; ++i) ac3[i] = (f32x4){0.f, 0.f, 0.f, 0.f};
    #pragma unroll
    for (int kt = 0; kt < 4; ++kt) {
        bf16x8 a = *(const bf16x8*)((const char*)A1 + abase + SWZB(arow, kt * 64 + lk * 16));
        #pragma unroll
        for (int ct = 0; ct < 8; ++ct) {
            int bc = ct * 16 + lm;
            bf16x8 b = *(const bf16x8*)((const char*)Bt + bc * 256 + SWZB(bc, kt * 64 + lk * 16));
            ac3[ct] = __builtin_amdgcn_mfma_f32_16x16x32_bf16(a, b, ac3[ct], 0, 0, 0);
        }
    }
    float v3[8][4];
    float s3[4] = {0, 0, 0, 0}, s32[4] = {0, 0, 0, 0};
    #pragma unroll
    for (int ct = 0; ct < 8; ++ct) {
        float fb = Fb2[ct * 16 + lm];
        #pragma unroll
        for (int i = 0; i < 4; ++i) {
            float v = ac3[ct][i] + fb;
            v3[ct][i] = v;
            s3[i] += v; s32[i] += v * v;
        }
    }
    #pragma unroll
    for (int o = 8; o > 0; o >>= 1) {
        #pragma unroll
        for (int i = 0; i < 4; ++i) {
            s3[i] += __shfl_xor(s3[i], o);
            s32[i] += __shfl_xor(s32[i], o);
        }
    }
    #pragma unroll
    for (int i = 0; i < 4; ++i) {
        float mu = s3[i] * (1.f / DD);
        float var = s32[i] * (1.f / DD) - mu * mu;
        float rs = rsqrtf(var + EPS);
        int row = rbase + i;
        if (row < N) {
            #pragma unroll
            for (int ct = 0; ct < 8; ++ct) {
                int col = ct * 16 + lm;
                out[(size_t)row * DD + col] = xk[ct][i] + (v3[ct][i] - mu) * rs * glr[ct] + blr[ct];
            }
        }
    }
}

extern "C" void kernel_launch(void* const* d_in, const int* in_sizes, int n_in,
                              void* d_out, int out_size, void* d_ws, size_t ws_size,
                              hipStream_t stream) {
    const float* h      = (const float*)d_in[0];
    const int*   gt_src = (const int*)d_in[1];
    const int*   gt_dst = (const int*)d_in[2];
    const int*   at_src = (const int*)d_in[3];
    const int*   at_dst = (const int*)d_in[4];
    const float* W1     = (const float*)d_in[5];
    const float* b1     = (const float*)d_in[6];
    const float* W2     = (const float*)d_in[7];
    const float* b2     = (const float*)d_in[8];
    const float* W3     = (const float*)d_in[9];
    const float* b3     = (const float*)d_in[10];
    const float* fW1    = (const float*)d_in[11];
    const float* fb1    = (const float*)d_in[12];
    const float* fW2    = (const float*)d_in[13];
    const float* fb2    = (const float*)d_in[14];
    const float* ln_g   = (const float*)d_in[15];
    const float* ln_b   = (const float*)d_in[16];

    const int E = in_sizes[1];
    const int N = in_sizes[0] / DD;
    const size_t NB = (size_t)N * DD;
    const int N2 = 2 * N;
    const int Btot = (N2 + BWIDTH - 1) >> BSH;
    const int n1 = 2 * Btot * NBLK1;

    // ---- workspace layout (combined bf16 tables) ----
    unsigned short* hb   = (unsigned short*)d_ws;          // NB bf16 (12.8 MB)
    unsigned short* bufA = hb + NB;                        // 2*NB bf16 (25.6 MB)
    unsigned short* bufB = bufA + 2 * NB;                  // 2*NB bf16 (25.6 MB)
    float* sm = (float*)(bufB + 2 * NB);
    float* norms = sm;  sm += N2;
    float* indeg = sm;  sm += N2;
    float* ssum  = sm;  sm += N2;
    float* cvec  = sm;  sm += NHEAD * DH + 32;
    unsigned short* Mtb  = (unsigned short*)sm;
    unsigned short* W1tb = Mtb + DD * DD;
    unsigned short* W2tb = W1tb + DD * DD;
    int* ip = (int*)(W2tb + DD * DD);
    int* rowptr = ip;  ip += ((N2 + 1 + 3) & ~3);
    int* csr    = ip;  ip += 2 * E;
    int* blkcnt = ip;  ip += ((n1 + 1 + 3) & ~3);
    int* scn    = ip;  ip += ((n1 + 1 + 3) & ~3);
    int* part   = ip;  ip += 256;
    // CSR-build scratch aliased over bufA (7.2 MB < 25.6 MB; bufA first written at stage 2)
    unsigned* pairs = (unsigned*)bufA;                     // 2E uint (4.8 MB)
    unsigned short* svals = (unsigned short*)(pairs + 2 * E);  // 2E ushort (2.4 MB)

    // fused weight prep (T in LDS; bit-identical to previous 3-kernel chain)
    k_wprep<<<NHEAD, 256, 0, stream>>>(W1, W2, W3, b1, b2, Mtb, cvec);
    k_wtb2 <<<128, 256, 0, stream>>>(fW1, fW2, W1tb, W2tb);

    const int TB = 256;
    // h -> bf16
    k_h2b<<<(int)(NB / 4 + TB - 1) / TB, TB, 0, stream>>>((const float4*)h, (ushort4*)hb,
                                                          (int)(NB / 4));
    // CSR build (no global atomics; packed intermediates)
    k_p1count<<<NBLK1, 256, 0, stream>>>(gt_src, gt_dst, at_src, at_dst, blkcnt, E, N, Btot);
    int nsb = (n1 + 1023) / 1024;
    k_scan1<<<nsb, 256, 0, stream>>>(blkcnt, scn, part, n1);
    k_scan2<<<1, 256, 0, stream>>>(part, nsb);
    k_scan3<<<(n1 + TB - 1) / TB, TB, 0, stream>>>(scn, part, n1, 4 * E);
    k_p1scatter<<<NBLK1, 256, 0, stream>>>(gt_src, gt_dst, at_src, at_dst, scn,
                                           pairs, svals, E, N, Btot);
    k_p2<<<Btot, 256, 0, stream>>>(pairs, svals, scn, rowptr, csr, indeg, norms,
                                   E, N2, Btot);

    // fused pull stages over combined [0,2N): 3 launches, 16 lanes/row uint4
    const int pgrid2 = (N2 + 15) / 16;
    k_pull_avgF<<<pgrid2, 256, 0, stream>>>((const uint4*)hb, rowptr, csr, norms,
                                            (uint4*)bufB, ssum, N, 1, 0);
    k_pull_avgF<<<pgrid2, 256, 0, stream>>>((const uint4*)bufB, rowptr, csr, norms,
                                            (uint4*)bufA, ssum, N, 0, 1);
    k_pull_sumF<<<pgrid2, 256, 0, stream>>>((const uint4*)bufA, rowptr, csr,
                                            (uint4*)bufB, N);
    unsigned short* Qb = bufB;

    // fused dense tail (MFMA bf16, 64 rows/block, 256 threads)
    k_tailm<<<(N + 63) / 64, 256, 0, stream>>>(Qb, Qb + NB, ssum, indeg, Mtb, W1tb, W2tb,
                                               cvec, b3, h, ln_g, ln_b, fb1, fb2,
                                               (float*)d_out, N);
}

// Round 15
// 245.329 us; speedup vs baseline: 1.6403x; 1.1261x over previous
//
#include <hip/hip_runtime.h>

#define DD 128
#define NHEAD 8
#define DH 16
#define EPS 1e-5f
#define BSH 9                 // bucket width 512 nodes
#define BWIDTH 512
#define NBLK1 256             // pass-1 blocks

typedef __attribute__((ext_vector_type(8))) short bf16x8;   // 8 bf16 = 4 VGPR
typedef __attribute__((ext_vector_type(4))) float f32x4;

// ---------- bf16 helpers (OCP bf16 = f32 upper half, RNE) ----------
__device__ inline unsigned short f2b(float f) {
    unsigned u = __float_as_uint(f);
    u += 0x7fffu + ((u >> 16) & 1);
    return (unsigned short)(u >> 16);
}
__device__ inline unsigned pk2(float lo, float hi) {
    return (unsigned)f2b(lo) | ((unsigned)f2b(hi) << 16);
}
// unpack-accumulate 8 bf16 (uint4 = 16 B) into a[8]
__device__ inline void upacc(uint4 u, float* a) {
    a[0] += __uint_as_float(u.x << 16);
    a[1] += __uint_as_float(u.x & 0xffff0000u);
    a[2] += __uint_as_float(u.y << 16);
    a[3] += __uint_as_float(u.y & 0xffff0000u);
    a[4] += __uint_as_float(u.z << 16);
    a[5] += __uint_as_float(u.z & 0xffff0000u);
    a[6] += __uint_as_float(u.w << 16);
    a[7] += __uint_as_float(u.w & 0xffff0000u);
}

// XOR swizzle for bf16 MFMA panels (row stride 256 B): keeps 16B alignment.
#define SWZB(row, off) ((off) ^ (((row) & 7) << 4))

// ================= h -> bf16 copy =================
__global__ void k_h2b(const float4* __restrict__ h4, ushort4* __restrict__ hb, int n4) {
    int i = blockIdx.x * 256 + threadIdx.x;
    if (i < n4) {
        float4 v = h4[i];
        hb[i] = make_ushort4(f2b(v.x), f2b(v.y), f2b(v.z), f2b(v.w));
    }
}

// ================= pass 1a: per-block bucket histograms =================
__global__ __launch_bounds__(256) void k_p1count(
        const int* __restrict__ gs, const int* __restrict__ gd,
        const int* __restrict__ as_, const int* __restrict__ ad,
        int* __restrict__ blkcnt, int E, int N, int Btot) {
    __shared__ int cnts[512];
    for (int j = threadIdx.x; j < 2 * Btot; j += 256) cnts[j] = 0;
    __syncthreads();
    int E2 = 2 * E;
    for (int i = blockIdx.x * 256 + threadIdx.x; i < E2; i += NBLK1 * 256) {
        int g = (i >= E);
        int e = g ? i - E : i;
        int s = g ? as_[e] : gs[e];
        int d = g ? ad[e] : gd[e];
        int cd = d + g * N, cs = s + g * N;
        atomicAdd(&cnts[cd >> BSH], 1);
        atomicAdd(&cnts[Btot + (cs >> BSH)], 1);
    }
    __syncthreads();
    for (int j = threadIdx.x; j < 2 * Btot; j += 256)
        blkcnt[j * NBLK1 + blockIdx.x] = cnts[j];
}

// ================= 3-stage scan =================
__global__ void k_scan1(const int* __restrict__ cnt, int* __restrict__ outv,
                        int* __restrict__ part, int n) {
    __shared__ int wsums[4];
    int t = threadIdx.x;
    int base = blockIdx.x * 1024 + t * 4;
    int v0 = 0, v1 = 0, v2 = 0, v3 = 0;
    if (base + 3 < n) {
        int4 q = *(const int4*)(cnt + base);
        v0 = q.x; v1 = q.y; v2 = q.z; v3 = q.w;
    } else {
        if (base < n)     v0 = cnt[base];
        if (base + 1 < n) v1 = cnt[base + 1];
        if (base + 2 < n) v2 = cnt[base + 2];
        if (base + 3 < n) v3 = cnt[base + 3];
    }
    int s0 = v0, s1 = s0 + v1, s2 = s1 + v2, s3 = s2 + v3;
    int x = s3;
    int lane = t & 63, w = t >> 6;
    for (int o = 1; o < 64; o <<= 1) { int u = __shfl_up(x, o); if (lane >= o) x += u; }
    if (lane == 63) wsums[w] = x;
    __syncthreads();
    int wo = 0;
    for (int i = 0; i < w; ++i) wo += wsums[i];
    int excl = wo + x - s3;
    if (base < n)     outv[base]     = excl;
    if (base + 1 < n) outv[base + 1] = excl + s0;
    if (base + 2 < n) outv[base + 2] = excl + s1;
    if (base + 3 < n) outv[base + 3] = excl + s2;
    if (t == 255) part[blockIdx.x] = wo + x;
}

__global__ void k_scan2(int* __restrict__ part, int nb) {
    __shared__ int ws[4];
    int t = threadIdx.x;
    int v = (t < nb) ? part[t] : 0;
    int x = v;
    int lane = t & 63, w = t >> 6;
    for (int o = 1; o < 64; o <<= 1) { int u = __shfl_up(x, o); if (lane >= o) x += u; }
    if (lane == 63) ws[w] = x;
    __syncthreads();
    int wo = 0;
    for (int i = 0; i < w; ++i) wo += ws[i];
    if (t < nb) part[t] = wo + x - v;
}

__global__ void k_scan3(int* __restrict__ outv, const int* __restrict__ part, int n, int total) {
    int i = blockIdx.x * blockDim.x + threadIdx.x;
    if (i < n) outv[i] += part[i >> 10];
    if (i == 0) outv[n] = total;
}

// ======== pass 1b: scatter edges into bucket regions (packed: local_d<<16 | src) ========
// requires N <= 65536 and BWIDTH <= 512 (src 16 bits, local 9 bits)
__global__ __launch_bounds__(256) void k_p1scatter(
        const int* __restrict__ gs, const int* __restrict__ gd,
        const int* __restrict__ as_, const int* __restrict__ ad,
        const int* __restrict__ scn, unsigned* __restrict__ pairs,
        unsigned short* __restrict__ svals, int E, int N, int Btot) {
    __shared__ int cur[512];
    for (int j = threadIdx.x; j < 2 * Btot; j += 256)
        cur[j] = scn[j * NBLK1 + blockIdx.x];
    __syncthreads();
    int E2 = 2 * E;
    for (int i = blockIdx.x * 256 + threadIdx.x; i < E2; i += NBLK1 * 256) {
        int g = (i >= E);
        int e = g ? i - E : i;
        int s = g ? as_[e] : gs[e];
        int d = g ? ad[e] : gd[e];
        int cd = d + g * N, cs = s + g * N;
        int pd = atomicAdd(&cur[cd >> BSH], 1);
        pairs[pd] = ((unsigned)(cd & (BWIDTH - 1)) << 16) | (unsigned)s;
        int ps = atomicAdd(&cur[Btot + (cs >> BSH)], 1);
        svals[ps - E2] = (unsigned short)(cs & (BWIDTH - 1));
    }
}

// ================= pass 2: per-bucket CSR + indeg + norms =================
__global__ __launch_bounds__(256) void k_p2(
        const unsigned* __restrict__ pairs, const unsigned short* __restrict__ svals,
        const int* __restrict__ scn, int* __restrict__ rowptr, int* __restrict__ csr,
        float* __restrict__ indeg, float* __restrict__ norms,
        int E, int N2, int Btot) {
    __shared__ int hist[BWIDTH];
    __shared__ int offs[BWIDTH];
    __shared__ int cur[BWIDTH];
    __shared__ int ws4[4];
    int b = blockIdx.x, t = threadIdx.x;
    int node0 = b << BSH;
    int W = N2 - node0; if (W > BWIDTH) W = BWIDTH;
    int Sd = scn[b * NBLK1], Ed = scn[(b + 1) * NBLK1];
    hist[t] = 0; hist[t + 256] = 0;
    __syncthreads();
    for (int i = Sd + t; i < Ed; i += 256)
        atomicAdd(&hist[pairs[i] >> 16], 1);
    __syncthreads();
    int a0 = hist[2 * t], a1 = hist[2 * t + 1];
    int sum2 = a0 + a1;
    int lane = t & 63, w = t >> 6;
    int x = sum2;
    for (int o = 1; o < 64; o <<= 1) { int u = __shfl_up(x, o); if (lane >= o) x += u; }
    if (lane == 63) ws4[w] = x;
    __syncthreads();
    int wo = 0;
    for (int i = 0; i < w; ++i) wo += ws4[i];
    int excl2 = wo + x - sum2;
    offs[2 * t] = excl2; offs[2 * t + 1] = excl2 + a0;
    cur[t] = 0; cur[t + 256] = 0;
    __syncthreads();
    for (int j = t; j < W; j += 256) {
        rowptr[node0 + j] = Sd + offs[j];
        indeg[node0 + j] = (float)hist[j];
    }
    if (b == 0 && t == 0) rowptr[N2] = 2 * E;
    for (int i = Sd + t; i < Ed; i += 256) {
        unsigned p = pairs[i];
        int l = p >> 16;
        int pos = atomicAdd(&cur[l], 1);
        csr[Sd + offs[l] + pos] = (int)(p & 0xffffu);
    }
    __syncthreads();
    hist[t] = 0; hist[t + 256] = 0;
    __syncthreads();
    int Ss = scn[(Btot + b) * NBLK1] - 2 * E;
    int Es = scn[(Btot + b + 1) * NBLK1] - 2 * E;
    for (int i = Ss + t; i < Es; i += 256)
        atomicAdd(&hist[svals[i]], 1);
    __syncthreads();
    for (int j = t; j < W; j += 256) {
        int od = hist[j];
        norms[node0 + j] = od > 0 ? rsqrtf((float)od) : 0.f;
    }
}

// ======== fused pull stage 1/2: avg (SAGE); 16 lanes/row, uint4 loads ========
__global__ __launch_bounds__(256) void k_pull_avgF(
        const uint4* __restrict__ xb, const int* __restrict__ rowptr,
        const int* __restrict__ csr, const float* __restrict__ norms,
        uint4* __restrict__ outb, float* __restrict__ ssum,
        int N, int shared_in, int doscale) {
    int cd = blockIdx.x * 16 + (threadIdx.x >> 4);
    int lane = threadIdx.x & 15;
    if (cd >= 2 * N) return;
    int gofs = (cd >= N) ? N : 0;
    int base = shared_in ? 0 : gofs;
    int beg = rowptr[cd], end = rowptr[cd + 1];
    float a[8];
    {
        uint4 u = xb[(size_t)(base + cd - gofs) * 16 + lane];   // self term
        a[0] = __uint_as_float(u.x << 16); a[1] = __uint_as_float(u.x & 0xffff0000u);
        a[2] = __uint_as_float(u.y << 16); a[3] = __uint_as_float(u.y & 0xffff0000u);
        a[4] = __uint_as_float(u.z << 16); a[5] = __uint_as_float(u.z & 0xffff0000u);
        a[6] = __uint_as_float(u.w << 16); a[7] = __uint_as_float(u.w & 0xffff0000u);
    }
    float ss = 0.f;
    int e = beg;
    int nb = end - e; if (nb > 16) nb = 16;
    int idx = (lane < nb) ? csr[e + lane] : 0;
    while (nb > 0) {
        int en = e + nb;
        int nbn = end - en; if (nbn > 16) nbn = 16;
        int idxn = (lane < nbn) ? csr[en + lane] : 0;           // prefetch next chunk
        #pragma unroll 8
        for (int d = 0; d < nb; ++d) {
            int s = __shfl(idx, d, 16);
            upacc(xb[(size_t)(base + s) * 16 + lane], a);
            if (doscale) ss += norms[base + s];
        }
        e = en; nb = nbn; idx = idxn;
    }
    float sc = 1.f / (float)(end - beg + 1);
    if (doscale) sc *= norms[cd];
    uint4 o;
    o.x = pk2(a[0] * sc, a[1] * sc); o.y = pk2(a[2] * sc, a[3] * sc);
    o.z = pk2(a[4] * sc, a[5] * sc); o.w = pk2(a[6] * sc, a[7] * sc);
    outb[(size_t)cd * 16 + lane] = o;
    if (doscale && lane == 0) ssum[cd] = ss;
}

// ======== fused pull stage 3: plain sum of pre-scaled rows -> bf16 Q (combined) ========
__global__ __launch_bounds__(256) void k_pull_sumF(
        const uint4* __restrict__ Pb, const int* __restrict__ rowptr,
        const int* __restrict__ csr, uint4* __restrict__ Qb, int N) {
    int cd = blockIdx.x * 16 + (threadIdx.x >> 4);
    int lane = threadIdx.x & 15;
    if (cd >= 2 * N) return;
    int base = (cd >= N) ? N : 0;
    int beg = rowptr[cd], end = rowptr[cd + 1];
    float a[8] = {0.f, 0.f, 0.f, 0.f, 0.f, 0.f, 0.f, 0.f};
    int e = beg;
    int nb = end - e; if (nb > 16) nb = 16;
    int idx = (lane < nb) ? csr[e + lane] : 0;
    while (nb > 0) {
        int en = e + nb;
        int nbn = end - en; if (nbn > 16) nbn = 16;
        int idxn = (lane < nbn) ? csr[en + lane] : 0;
        #pragma unroll 8
        for (int d = 0; d < nb; ++d) {
            int s = __shfl(idx, d, 16);
            upacc(Pb[(size_t)(base + s) * 16 + lane], a);
        }
        e = en; nb = nbn; idx = idxn;
    }
    uint4 o;
    o.x = pk2(a[0], a[1]); o.y = pk2(a[2], a[3]);
    o.z = pk2(a[4], a[5]); o.w = pk2(a[6], a[7]);
    Qb[(size_t)cd * 16 + lane] = o;
}

// ======== weight prep, k-split wide kernels (fixes latency-bound 8-block prep) ========
// k_wT: T[i][r][c] = sum_k W2[i][r][k] * W3[i][k][c]; 16 threads/output, 16 outputs/block.
__global__ __launch_bounds__(256) void k_wT(
        const float* __restrict__ W2, const float* __restrict__ W3, float* __restrict__ T) {
    int t = threadIdx.x;
    int o = blockIdx.x * 16 + (t >> 4);        // 0..16383
    int sub = t & 15;
    int i = o >> 11, oo = o & 2047;
    int r = oo >> 4, c = oo & 15;
    const float* w2 = W2 + (size_t)i * DD * DD + r * DD + sub * 8;
    const float* w3 = W3 + (size_t)i * DD * DH + c + sub * 8 * DH;
    float acc = 0.f;
    #pragma unroll
    for (int k = 0; k < 8; ++k) acc += w2[k] * w3[k * DH];
    #pragma unroll
    for (int m = 8; m; m >>= 1) acc += __shfl_xor(acc, m);
    if (sub == 0) T[o] = acc;
}

// k_wM: Mtb[(i*16+c)*128 + r] = bf16( sum_k W1[i][r][k] * T[i][k][c] )
__global__ __launch_bounds__(256) void k_wM(
        const float* __restrict__ W1, const float* __restrict__ T,
        unsigned short* __restrict__ Mtb) {
    int t = threadIdx.x;
    int o = blockIdx.x * 16 + (t >> 4);
    int sub = t & 15;
    int i = o >> 11, oo = o & 2047;
    int r = oo >> 4, c = oo & 15;
    const float* w1 = W1 + (size_t)i * DD * DD + r * DD + sub * 8;
    const float* tt = T + (size_t)i * DD * DH + c + sub * 8 * DH;
    float acc = 0.f;
    #pragma unroll
    for (int k = 0; k < 8; ++k) acc += w1[k] * tt[k * DH];
    #pragma unroll
    for (int m = 8; m; m >>= 1) acc += __shfl_xor(acc, m);
    if (sub == 0) Mtb[(size_t)(i * DH + c) * DD + r] = f2b(acc);
}

// k_cvec2: cvec[i][c] = sum_k b1[i][k]*T[i][k][c] + b2[i][k]*W3[i][k][c]; grid = 8 heads
__global__ __launch_bounds__(256) void k_cvec2(
        const float* __restrict__ b1, const float* __restrict__ b2,
        const float* __restrict__ T, const float* __restrict__ W3,
        float* __restrict__ cvec) {
    int i = blockIdx.x, t = threadIdx.x;
    int c = t >> 4, sub = t & 15;
    const float* tt = T + (size_t)i * DD * DH + c + sub * 8 * DH;
    const float* w3 = W3 + (size_t)i * DD * DH + c + sub * 8 * DH;
    const float* p1 = b1 + i * DD + sub * 8;
    const float* p2 = b2 + i * DD + sub * 8;
    float acc = 0.f;
    #pragma unroll
    for (int k = 0; k < 8; ++k) acc += p1[k] * tt[k * DH] + p2[k] * w3[k * DH];
    #pragma unroll
    for (int m = 8; m; m >>= 1) acc += __shfl_xor(acc, m);
    if (sub == 0) cvec[i * DH + c] = acc;
}

// transpose + bf16 both FFN weights in one launch (128 blocks)
__global__ void k_wtb2(const float* __restrict__ fW1, const float* __restrict__ fW2,
                       unsigned short* __restrict__ W1tb, unsigned short* __restrict__ W2tb) {
    int idx = blockIdx.x * 256 + threadIdx.x;      // 32768 total
    int which = idx >> 14;
    int o = idx & 16383;
    int c = o >> 7, k = o & 127;
    const float* W = which ? fW2 : fW1;
    unsigned short* Wt = which ? W2tb : W1tb;
    Wt[c * DD + k] = f2b(W[(size_t)k * DD + c]);
}

// ================= fused tail, MFMA bf16: 64 rows/block, 4 waves =================
__global__ __launch_bounds__(256) void k_tailm(
        const unsigned short* __restrict__ Qgtb, const unsigned short* __restrict__ Qatb,
        const float* __restrict__ ssum, const float* __restrict__ indeg,
        const unsigned short* __restrict__ Mtb, const unsigned short* __restrict__ W1tb,
        const unsigned short* __restrict__ W2tb,
        const float* __restrict__ cvec, const float* __restrict__ b3,
        const float* __restrict__ h, const float* __restrict__ ln_g,
        const float* __restrict__ ln_b, const float* __restrict__ Fb1,
        const float* __restrict__ Fb2, float* __restrict__ out, int N) {
    __shared__ __align__(16) unsigned short A0[64 * DD];   // 16 KB: Qgt -> x panel
    __shared__ __align__(16) unsigned short A1[64 * DD];   // 16 KB: Qat -> f1 panel
    __shared__ __align__(16) unsigned short Bt[DD * DD];   // 32 KB: weight panel [col][k]
    int t = threadIdx.x;
    int w = t >> 6, l = t & 63;
    int lm = l & 15, lk = l >> 4;
    int row0 = blockIdx.x * 64;

    // ---- stage A panels (Q bf16, swizzled) ----
    for (int i = t; i < 1024; i += 256) {
        int r = i >> 4, ch = i & 15;
        int gr = row0 + r; if (gr >= N) gr = N - 1;
        uint4 v0 = *(const uint4*)(Qgtb + (size_t)gr * DD + ch * 8);
        uint4 v1 = *(const uint4*)(Qatb + (size_t)gr * DD + ch * 8);
        *(uint4*)((char*)A0 + r * 256 + SWZB(r, ch * 16)) = v0;
        *(uint4*)((char*)A1 + r * 256 + SWZB(r, ch * 16)) = v1;
    }
    // ---- stage Bt = Mtb ----
    for (int i = t; i < 2048; i += 256) {
        int c = i >> 4, ch = i & 15;
        uint4 v = *(const uint4*)(Mtb + (size_t)c * DD + ch * 8);
        *(uint4*)((char*)Bt + c * 256 + SWZB(c, ch * 16)) = v;
    }
    __syncthreads();

    int arow = w * 16 + lm;
    int abase = arow * 256;

    // ---- GEMM1 ----
    f32x4 acc[8];
    #pragma unroll
    for (int i = 0; i < 8; ++i) acc[i] = (f32x4){0.f, 0.f, 0.f, 0.f};
    #pragma unroll
    for (int kt = 0; kt < 4; ++kt) {
        int aoff = abase + SWZB(arow, kt * 64 + lk * 16);
        bf16x8 ag = *(const bf16x8*)((const char*)A0 + aoff);
        bf16x8 aa = *(const bf16x8*)((const char*)A1 + aoff);
        #pragma unroll
        for (int ct = 0; ct < 8; ++ct) {
            int bc = ct * 16 + lm;
            bf16x8 b = *(const bf16x8*)((const char*)Bt + bc * 256 + SWZB(bc, kt * 64 + lk * 16));
            acc[ct] = __builtin_amdgcn_mfma_f32_16x16x32_bf16(
                ((ct >> 1) & 1) ? aa : ag, b, acc[ct], 0, 0, 0);
        }
    }

    // ---- epilogue 1: (acc + ss*c)*nd + b3, LN over 128 cols, + h residual ----
    int rbase = row0 + w * 16 + lk * 4;
    float ssv[2][4], ndv[2][4];
    #pragma unroll
    for (int i = 0; i < 4; ++i) {
        int rc = rbase + i; if (rc >= N) rc = N - 1;
        #pragma unroll
        for (int g2 = 0; g2 < 2; ++g2) {
            ssv[g2][i] = ssum[g2 * N + rc];
            float id = indeg[g2 * N + rc];
            ndv[g2][i] = id > 0.f ? rsqrtf(id) : 0.f;
        }
    }
    float glr[8], blr[8];
    #pragma unroll
    for (int ct = 0; ct < 8; ++ct) {
        glr[ct] = ln_g[ct * 16 + lm];
        blr[ct] = ln_b[ct * 16 + lm];
    }
    float vv[8][4];
    float s[4] = {0, 0, 0, 0}, s2[4] = {0, 0, 0, 0};
    #pragma unroll
    for (int ct = 0; ct < 8; ++ct) {
        int col = ct * 16 + lm;
        int g2 = (ct >> 1) & 1;
        float cvv = cvec[col], b3v = b3[col];
        #pragma unroll
        for (int i = 0; i < 4; ++i) {
            float v = (acc[ct][i] + ssv[g2][i] * cvv) * ndv[g2][i] + b3v;
            vv[ct][i] = v;
            s[i] += v; s2[i] += v * v;
        }
    }
    #pragma unroll
    for (int o = 8; o > 0; o >>= 1) {
        #pragma unroll
        for (int i = 0; i < 4; ++i) {
            s[i] += __shfl_xor(s[i], o);
            s2[i] += __shfl_xor(s2[i], o);
        }
    }
    __syncthreads();                        // all GEMM1 LDS reads done
    float xk[8][4];
    #pragma unroll
    for (int i = 0; i < 4; ++i) {
        float mu = s[i] * (1.f / DD);
        float var = s2[i] * (1.f / DD) - mu * mu;
        float rs = rsqrtf(var + EPS);
        int row = rbase + i; int rc = row < N ? row : N - 1;
        int lrow = w * 16 + lk * 4 + i;
        #pragma unroll
        for (int ct = 0; ct < 8; ++ct) {
            int col = ct * 16 + lm;
            float x = h[(size_t)rc * DD + col] + (vv[ct][i] - mu) * rs * glr[ct] + blr[ct];
            xk[ct][i] = x;
            *(unsigned short*)((char*)A0 + lrow * 256 + SWZB(lrow, 2 * col)) = f2b(x);
        }
    }
    for (int i = t; i < 2048; i += 256) {   // stage Bt = W1tb
        int c = i >> 4, ch = i & 15;
        uint4 v = *(const uint4*)(W1tb + (size_t)c * DD + ch * 8);
        *(uint4*)((char*)Bt + c * 256 + SWZB(c, ch * 16)) = v;
    }
    __syncthreads();

    // ---- GEMM2: f1 = relu(x @ fW1 + Fb1) ----
    f32x4 ac2[8];
    #pragma unroll
    for (int i = 0; i < 8; ++i) ac2[i] = (f32x4){0.f, 0.f, 0.f, 0.f};
    #pragma unroll
    for (int kt = 0; kt < 4; ++kt) {
        bf16x8 a = *(const bf16x8*)((const char*)A0 + abase + SWZB(arow, kt * 64 + lk * 16));
        #pragma unroll
        for (int ct = 0; ct < 8; ++ct) {
            int bc = ct * 16 + lm;
            bf16x8 b = *(const bf16x8*)((const char*)Bt + bc * 256 + SWZB(bc, kt * 64 + lk * 16));
            ac2[ct] = __builtin_amdgcn_mfma_f32_16x16x32_bf16(a, b, ac2[ct], 0, 0, 0);
        }
    }
    #pragma unroll
    for (int i = 0; i < 4; ++i) {
        int lrow = w * 16 + lk * 4 + i;
        #pragma unroll
        for (int ct = 0; ct < 8; ++ct) {
            int col = ct * 16 + lm;
            float f = ac2[ct][i] + Fb1[col];
            *(unsigned short*)((char*)A1 + lrow * 256 + SWZB(lrow, 2 * col)) =
                f2b(f > 0.f ? f : 0.f);
        }
    }
    __syncthreads();                        // GEMM2 Bt reads + f1 writes done
    for (int i = t; i < 2048; i += 256) {   // stage Bt = W2tb
        int c = i >> 4, ch = i & 15;
        uint4 v = *(const uint4*)(W2tb + (size_t)c * DD + ch * 8);
        *(uint4*)((char*)Bt + c * 256 + SWZB(c, ch * 16)) = v;
    }
    __syncthreads();

    // ---- GEMM3: out = x + LN(f1 @ fW2 + Fb2) ----
    f32x4 ac3[8];
    #pragma unroll
    for (int i = 0; i < 8; ++i) ac3[i] = (f32x4){0.f, 0.f, 0.f, 0.f};
    #pragma unroll
    for (int kt = 0; kt < 4; ++kt) {
        bf16x8 a = *(const bf16x8*)((const char*)A1 + abase + SWZB(arow, kt * 64 + lk * 16));
        #pragma unroll
        for (int ct = 0; ct < 8; ++ct) {
            int bc = ct * 16 + lm;
            bf16x8 b = *(const bf16x8*)((const char*)Bt + bc * 256 + SWZB(bc, kt * 64 + lk * 16));
            ac3[ct] = __builtin_amdgcn_mfma_f32_16x16x32_bf16(a, b, ac3[ct], 0, 0, 0);
        }
    }
    float v3[8][4];
    float s3[4] = {0, 0, 0, 0}, s32[4] = {0, 0, 0, 0};
    #pragma unroll
    for (int ct = 0; ct < 8; ++ct) {
        float fb = Fb2[ct * 16 + lm];
        #pragma unroll
        for (int i = 0; i < 4; ++i) {
            float v = ac3[ct][i] + fb;
            v3[ct][i] = v;
            s3[i] += v; s32[i] += v * v;
        }
    }
    #pragma unroll
    for (int o = 8; o > 0; o >>= 1) {
        #pragma unroll
        for (int i = 0; i < 4; ++i) {
            s3[i] += __shfl_xor(s3[i], o);
            s32[i] += __shfl_xor(s32[i], o);
        }
    }
    #pragma unroll
    for (int i = 0; i < 4; ++i) {
        float mu = s3[i] * (1.f / DD);
        float var = s32[i] * (1.f / DD) - mu * mu;
        float rs = rsqrtf(var + EPS);
        int row = rbase + i;
        if (row < N) {
            #pragma unroll
            for (int ct = 0; ct < 8; ++ct) {
                int col = ct * 16 + lm;
                out[(size_t)row * DD + col] = xk[ct][i] + (v3[ct][i] - mu) * rs * glr[ct] + blr[ct];
            }
        }
    }
}

extern "C" void kernel_launch(void* const* d_in, const int* in_sizes, int n_in,
                              void* d_out, int out_size, void* d_ws, size_t ws_size,
                              hipStream_t stream) {
    const float* h      = (const float*)d_in[0];
    const int*   gt_src = (const int*)d_in[1];
    const int*   gt_dst = (const int*)d_in[2];
    const int*   at_src = (const int*)d_in[3];
    const int*   at_dst = (const int*)d_in[4];
    const float* W1     = (const float*)d_in[5];
    const float* b1     = (const float*)d_in[6];
    const float* W2     = (const float*)d_in[7];
    const float* b2     = (const float*)d_in[8];
    const float* W3     = (const float*)d_in[9];
    const float* b3     = (const float*)d_in[10];
    const float* fW1    = (const float*)d_in[11];
    const float* fb1    = (const float*)d_in[12];
    const float* fW2    = (const float*)d_in[13];
    const float* fb2    = (const float*)d_in[14];
    const float* ln_g   = (const float*)d_in[15];
    const float* ln_b   = (const float*)d_in[16];

    const int E = in_sizes[1];
    const int N = in_sizes[0] / DD;
    const size_t NB = (size_t)N * DD;
    const int N2 = 2 * N;
    const int Btot = (N2 + BWIDTH - 1) >> BSH;
    const int n1 = 2 * Btot * NBLK1;

    // ---- workspace layout (combined bf16 tables) ----
    unsigned short* hb   = (unsigned short*)d_ws;          // NB bf16 (12.8 MB)
    unsigned short* bufA = hb + NB;                        // 2*NB bf16 (25.6 MB)
    unsigned short* bufB = bufA + 2 * NB;                  // 2*NB bf16 (25.6 MB)
    float* sm = (float*)(bufB + 2 * NB);
    float* norms = sm;  sm += N2;
    float* indeg = sm;  sm += N2;
    float* ssum  = sm;  sm += N2;
    float* cvec  = sm;  sm += NHEAD * DH + 32;
    float* Tm    = sm;  sm += NHEAD * DD * DH;             // 16384 f32 (64 KB)
    unsigned short* Mtb  = (unsigned short*)sm;
    unsigned short* W1tb = Mtb + DD * DD;
    unsigned short* W2tb = W1tb + DD * DD;
    int* ip = (int*)(W2tb + DD * DD);
    int* rowptr = ip;  ip += ((N2 + 1 + 3) & ~3);
    int* csr    = ip;  ip += 2 * E;
    int* blkcnt = ip;  ip += ((n1 + 1 + 3) & ~3);
    int* scn    = ip;  ip += ((n1 + 1 + 3) & ~3);
    int* part   = ip;  ip += 256;
    // CSR-build scratch aliased over bufA (7.2 MB < 25.6 MB; bufA first written at stage 2)
    unsigned* pairs = (unsigned*)bufA;                     // 2E uint (4.8 MB)
    unsigned short* svals = (unsigned short*)(pairs + 2 * E);  // 2E ushort (2.4 MB)

    // wide k-split weight prep (latency-hidden)
    k_wT   <<<1024, 256, 0, stream>>>(W2, W3, Tm);
    k_wM   <<<1024, 256, 0, stream>>>(W1, Tm, Mtb);
    k_cvec2<<<NHEAD, 256, 0, stream>>>(b1, b2, Tm, W3, cvec);
    k_wtb2 <<<128, 256, 0, stream>>>(fW1, fW2, W1tb, W2tb);

    const int TB = 256;
    // h -> bf16
    k_h2b<<<(int)(NB / 4 + TB - 1) / TB, TB, 0, stream>>>((const float4*)h, (ushort4*)hb,
                                                          (int)(NB / 4));
    // CSR build (no global atomics; packed intermediates)
    k_p1count<<<NBLK1, 256, 0, stream>>>(gt_src, gt_dst, at_src, at_dst, blkcnt, E, N, Btot);
    int nsb = (n1 + 1023) / 1024;
    k_scan1<<<nsb, 256, 0, stream>>>(blkcnt, scn, part, n1);
    k_scan2<<<1, 256, 0, stream>>>(part, nsb);
    k_scan3<<<(n1 + TB - 1) / TB, TB, 0, stream>>>(scn, part, n1, 4 * E);
    k_p1scatter<<<NBLK1, 256, 0, stream>>>(gt_src, gt_dst, at_src, at_dst, scn,
                                           pairs, svals, E, N, Btot);
    k_p2<<<Btot, 256, 0, stream>>>(pairs, svals, scn, rowptr, csr, indeg, norms,
                                   E, N2, Btot);

    // fused pull stages over combined [0,2N): 3 launches, 16 lanes/row uint4
    const int pgrid2 = (N2 + 15) / 16;
    k_pull_avgF<<<pgrid2, 256, 0, stream>>>((const uint4*)hb, rowptr, csr, norms,
                                            (uint4*)bufB, ssum, N, 1, 0);
    k_pull_avgF<<<pgrid2, 256, 0, stream>>>((const uint4*)bufB, rowptr, csr, norms,
                                            (uint4*)bufA, ssum, N, 0, 1);
    k_pull_sumF<<<pgrid2, 256, 0, stream>>>((const uint4*)bufA, rowptr, csr,
                                            (uint4*)bufB, N);
    unsigned short* Qb = bufB;

    // fused dense tail (MFMA bf16, 64 rows/block, 256 threads)
    k_tailm<<<(N + 63) / 64, 256, 0, stream>>>(Qb, Qb + NB, ssum, indeg, Mtb, W1tb, W2tb,
                                               cvec, b3, h, ln_g, ln_b, fb1, fb2,
                                               (float*)d_out, N);
}